// Round 6
// baseline (989.801 us; speedup 1.0000x reference)
//
#include <hip/hip_runtime.h>
#include <math.h>

// Problem constants
#define BSZ 8
#define CW  32      // WIDTH (channels)
#define NN  256     // NX = NY
#define MM  16      // modes M1 = M2
#define NL  4
#define HID 128

// Anti-rematerialization pin: opaque asm def forces values to stay VGPR-resident
// (compiler would otherwise re-load read-only global data inside inner loops).
#define PIN4(a,b,c,d) asm volatile("" : "+v"(a), "+v"(b), "+v"(c), "+v"(d))
#define PIN32(A) do { \
    PIN4(A[0],A[1],A[2],A[3]);     PIN4(A[4],A[5],A[6],A[7]); \
    PIN4(A[8],A[9],A[10],A[11]);   PIN4(A[12],A[13],A[14],A[15]); \
    PIN4(A[16],A[17],A[18],A[19]); PIN4(A[20],A[21],A[22],A[23]); \
    PIN4(A[24],A[25],A[26],A[27]); PIN4(A[28],A[29],A[30],A[31]); \
} while (0)
#define PIN16(A) do { \
    PIN4(A[0],A[1],A[2],A[3]);     PIN4(A[4],A[5],A[6],A[7]); \
    PIN4(A[8],A[9],A[10],A[11]);   PIN4(A[12],A[13],A[14],A[15]); \
} while (0)

// ---------------------------------------------------------------------------
// Fast exact-erf GELU: Abramowitz-Stegun 7.1.26 (max |err| 1.5e-7), branchless.
// ---------------------------------------------------------------------------
static __device__ __forceinline__ float gelu_f(float v) {
    float au = fabsf(v) * 0.70710678118654752f;
    float t  = __builtin_amdgcn_rcpf(fmaf(0.3275911f, au, 1.0f));
    float p  = fmaf(fmaf(fmaf(fmaf(1.061405429f, t, -1.453152027f),
                              t, 1.421413741f),
                         t, -0.284496736f),
                    t, 0.254829592f) * t;
    float e  = __expf(-au * au);
    float E  = fmaf(-p, e, 1.0f);          // erf(|v|/sqrt2)
    return fmaf(0.5f * fabsf(v), E, 0.5f * v);
}

#define TWO_PI_OVER_N (6.28318530717958647692f / 256.0f)

// ---------------------------------------------------------------------------
// Build forward-DFT twiddle matrix Wf[y][2*ky+p]: p=0 -> cos, p=1 -> -sin
// ---------------------------------------------------------------------------
__global__ void k_twiddle(float* __restrict__ Wf) {
    int idx = blockIdx.x * 256 + threadIdx.x;   // 8192 = 256 y * 32 c
    int y = idx >> 5, c = idx & 31;
    int ky = c >> 1, p = c & 1;
    int m = (ky * y) & 255;
    float ang = (float)m * TWO_PI_OVER_N;
    Wf[idx] = p ? -sinf(ang) : cosf(ang);
}

// ---------------------------------------------------------------------------
// Transpose decoder weights: w1t[d][o][i] <- w1[d][i][o]; w2t[d][j][i] <- w2[d][i][j]
// ---------------------------------------------------------------------------
__global__ void k_prep_dec(const float* __restrict__ w1, const float* __restrict__ w2,
                           float* __restrict__ w1t, float* __restrict__ w2t) {
    int tid = threadIdx.x;
    for (int idx = tid; idx < 3 * 32 * 32; idx += 256) {
        int d = idx >> 10, r = idx & 1023, o = r >> 5, i = r & 31;
        w1t[idx] = w1[d * 1024 + i * 32 + o];
    }
    for (int idx = tid; idx < 3 * 128 * 32; idx += 256) {
        int d = idx >> 12, r = idx & 4095, j = r >> 5, i = r & 31;
        w2t[idx] = w2[d * 4096 + i * 128 + j];
    }
}

// ---------------------------------------------------------------------------
// Lifting
// ---------------------------------------------------------------------------
__global__ void k_lift(const float* __restrict__ bc, const float* __restrict__ xg,
                       const float* __restrict__ yg, const float* __restrict__ w,
                       const float* __restrict__ bias, float* __restrict__ h) {
    int idx = blockIdx.x * 256 + threadIdx.x;   // over B*N*N
    int b = idx >> 16, pos = idx & 65535;
    float i0 = bc[b * 3 + 0], i1 = bc[b * 3 + 1], i2 = bc[b * 3 + 2];
    float i3 = xg[idx], i4 = yg[idx];
#pragma unroll
    for (int c = 0; c < CW; ++c) {
        float v = i0 * w[c] + i1 * w[CW + c] + i2 * w[2 * CW + c]
                + i3 * w[3 * CW + c] + i4 * w[4 * CW + c] + bias[c];
        h[((size_t)(b * CW + c) << 16) + pos] = v;
    }
}

// ---------------------------------------------------------------------------
// Forward DFT along y as GEMM vs Wf. 4 waves; wave wv owns y-quarter,
// lane l owns row blockIdx*64+l. Wf wave-uniform -> s_load. LDS reduce.
// gy layout: (row, c) with c = 2*ky+part
// ---------------------------------------------------------------------------
__global__ void k_fwd_y(const float* __restrict__ h, const float* __restrict__ Wf,
                        float* __restrict__ gy) {
    __shared__ float red[4][64][33];   // padded
    int tid = threadIdx.x;
    int wv = tid >> 6, lane = tid & 63;
    int row0 = blockIdx.x * 64;
    const float* hp = h + (size_t)(row0 + lane) * 256 + wv * 64;
    const float* wp = Wf + wv * 64 * 32;
    float acc[32];
#pragma unroll
    for (int c = 0; c < 32; ++c) acc[c] = 0.f;
#pragma unroll 4
    for (int yy = 0; yy < 64; yy += 4) {
        float4 hv = *(const float4*)(hp + yy);
        const float* wr0 = wp + yy * 32;
#pragma unroll
        for (int c = 0; c < 32; ++c) acc[c] += hv.x * wr0[c];
#pragma unroll
        for (int c = 0; c < 32; ++c) acc[c] += hv.y * wr0[32 + c];
#pragma unroll
        for (int c = 0; c < 32; ++c) acc[c] += hv.z * wr0[64 + c];
#pragma unroll
        for (int c = 0; c < 32; ++c) acc[c] += hv.w * wr0[96 + c];
    }
#pragma unroll
    for (int c = 0; c < 32; ++c) red[wv][lane][c] = acc[c];
    __syncthreads();
#pragma unroll
    for (int k = 0; k < 8; ++k) {
        int o = k * 256 + tid;          // 0..2047
        int r = o >> 5, c = o & 31;
        float v = red[0][r][c] + red[1][r][c] + red[2][r][c] + red[3][r][c];
        gy[(size_t)(row0 + r) * 32 + c] = v;
    }
}

// ---------------------------------------------------------------------------
// Forward DFT along x, 1024 threads: thread = (t = kx*16+ky, xq = tid>>8).
// Each thread sums 64 x values (split-K), LDS-reduce 4 partials.
// ---------------------------------------------------------------------------
__global__ void __launch_bounds__(1024) k_fwd_x(const float* __restrict__ gy,
                                                float* __restrict__ Xf) {
    __shared__ float g[8192];           // (x, c) 32 KB
    __shared__ float part[4][256][2];   // 8 KB
    __shared__ float ct[256], st[256];
    int tid = threadIdx.x;
    if (tid < 256) {
        float ang = (float)tid * TWO_PI_OVER_N;
        ct[tid] = cosf(ang);
        st[tid] = sinf(ang);
    }
    size_t base = (size_t)blockIdx.x * 8192;
#pragma unroll
    for (int j = 0; j < 8; ++j) g[j * 1024 + tid] = gy[base + j * 1024 + tid];
    __syncthreads();

    int t = tid & 255, xq = tid >> 8;
    int kx = t >> 4, ky = t & 15;
    float ar = 0.f, ai = 0.f;
    int x0 = xq * 64;
    int idx = (kx * x0) & 255;
#pragma unroll 4
    for (int x = x0; x < x0 + 64; ++x) {
        float c = ct[idx], s = st[idx];
        float gr = g[x * 32 + ky * 2], gi = g[x * 32 + ky * 2 + 1];
        ar += gr * c + gi * s;          // e^{-i}
        ai += gi * c - gr * s;
        idx = (idx + kx) & 255;
    }
    part[xq][t][0] = ar;
    part[xq][t][1] = ai;
    __syncthreads();
    if (tid < 256) {
        float a0 = part[0][tid][0] + part[1][tid][0] + part[2][tid][0] + part[3][tid][0];
        float a1 = part[0][tid][1] + part[1][tid][1] + part[2][tid][1] + part[3][tid][1];
        Xf[((size_t)blockIdx.x * 256 + tid) * 2 + 0] = a0 * (1.0f / 256.0f);
        Xf[((size_t)blockIdx.x * 256 + tid) * 2 + 1] = a1 * (1.0f / 256.0f);
    }
}

// ---------------------------------------------------------------------------
// Fused mode-mix + inverse x-DFT, 1024 threads. Block = (b,o), grid 256.
// ---------------------------------------------------------------------------
__global__ void __launch_bounds__(1024) k_spec(const float* __restrict__ Xf,
                                               const float* __restrict__ wr,
                                               const float* __restrict__ wi,
                                               float* __restrict__ gi) {
    __shared__ float tl[512];
    __shared__ float pp[4][256][2];
    __shared__ float ct[256], st[256];
    int tid = threadIdx.x;
    if (tid < 256) {
        float ang = (float)tid * TWO_PI_OVER_N;
        ct[tid] = cosf(ang);
        st[tid] = sinf(ang);
    }
    int b = blockIdx.x >> 5, o = blockIdx.x & 31;
    int t = tid & 255, ig = tid >> 8;

    // phase 1: mix (split-K over i)
    float tr = 0.f, ti = 0.f;
    const float2* xp = (const float2*)Xf + (size_t)b * 8192 + t;
    const float* wrp = wr + (size_t)o * 256 + t;
    const float* wip = wi + (size_t)o * 256 + t;
#pragma unroll
    for (int i = ig * 8; i < ig * 8 + 8; ++i) {
        float2 xv = xp[i * 256];
        float wrv = wrp[(size_t)i * 8192];
        float wiv = wip[(size_t)i * 8192];
        tr += xv.x * wrv - xv.y * wiv;
        ti += xv.x * wiv + xv.y * wrv;
    }
    pp[ig][t][0] = tr;
    pp[ig][t][1] = ti;
    __syncthreads();
    if (tid < 256) {
        tl[tid * 2 + 0] = pp[0][tid][0] + pp[1][tid][0] + pp[2][tid][0] + pp[3][tid][0];
        tl[tid * 2 + 1] = pp[0][tid][1] + pp[1][tid][1] + pp[2][tid][1] + pp[3][tid][1];
    }
    __syncthreads();

    // phase 2: inverse x-DFT; thread handles 4 ky for one x
    int x = t, kg = ig;
    float gre[4], gim[4];
#pragma unroll
    for (int k = 0; k < 4; ++k) { gre[k] = 0.f; gim[k] = 0.f; }
#pragma unroll 4
    for (int kx = 0; kx < 16; ++kx) {
        int idx = (kx * x) & 255;
        float c = ct[idx], s = st[idx];
#pragma unroll
        for (int k = 0; k < 4; ++k) {
            int ky = kg * 4 + k;
            float t2r = tl[(kx * 16 + ky) * 2 + 0];
            float t2i = tl[(kx * 16 + ky) * 2 + 1];
            gre[k] += t2r * c - t2i * s;   // e^{+i}
            gim[k] += t2i * c + t2r * s;
        }
    }
    size_t ob = (((size_t)b * 256 + x) * 32 + o) * 32;
#pragma unroll
    for (int k = 0; k < 4; ++k) {
        gi[ob + (kg * 4 + k) * 2 + 0] = gre[k];
        gi[ob + (kg * 4 + k) * 2 + 1] = gim[k];
    }
}

// ---------------------------------------------------------------------------
// Fused inverse-y DFT (c2r) + pointwise + GELU + residual.
// hv/cy/sy pinned in VGPRs (anti-remat) -> no per-o reloads.
// ---------------------------------------------------------------------------
__global__ void __launch_bounds__(256, 4) k_update(float* __restrict__ h,
                         const float* __restrict__ gi,
                         const float* __restrict__ pww, const float* __restrict__ pwb) {
    __shared__ float ct[256], st[256];
    int tid = threadIdx.x;
    int bx = blockIdx.x;               // b*256 + x
    int b = bx >> 8, x = bx & 255;
    {
        float ang = (float)tid * TWO_PI_OVER_N;
        ct[tid] = cosf(ang);
        st[tid] = sinf(ang);
    }
    __syncthreads();

    int y = tid;
    size_t hbase = ((size_t)b * 32) << 16;
    float hv[32];
#pragma unroll
    for (int i = 0; i < 32; ++i) hv[i] = h[hbase + ((size_t)i << 16) + x * 256 + y];
    PIN32(hv);
    float cy[16], sy[16];
#pragma unroll
    for (int ky = 0; ky < 16; ++ky) {
        int m = (ky * y) & 255;
        cy[ky] = ct[m];
        sy[ky] = st[m];
    }
    PIN16(cy);
    PIN16(sy);
    const float* gp = gi + (size_t)bx * 1024;
#pragma unroll 4
    for (int o = 0; o < 32; ++o) {
        const float* go = gp + o * 32;       // uniform -> s_load
        float sc = 0.5f * go[0];             // cy[0]=1, sy[0]=0
#pragma unroll
        for (int ky = 1; ky < 16; ++ky)
            sc += go[ky * 2] * cy[ky] - go[ky * 2 + 1] * sy[ky];
        sc *= (2.0f / 256.0f);
        const float* wo = pww + o * 32;      // uniform -> s_load
        float pw = pwb[o];
#pragma unroll
        for (int i = 0; i < 32; ++i) pw += hv[i] * wo[i];
        float u = sc + pw;
        h[hbase + ((size_t)o << 16) + x * 256 + y] = hv[o] + gelu_f(u);
    }
}

// ---------------------------------------------------------------------------
// Decoder: pre-transposed weights via s_load; hf and z1 pinned in VGPRs.
// ---------------------------------------------------------------------------
__global__ void __launch_bounds__(256, 4) k_decode(const float* __restrict__ h,
                         const float* __restrict__ w1t, const float* __restrict__ b1,
                         const float* __restrict__ w2t, const float* __restrict__ b2,
                         const float* __restrict__ w3, const float* __restrict__ b3,
                         float* __restrict__ out) {
    int g = blockIdx.x * 256 + threadIdx.x;
    int b = g >> 16, pos = g & 65535;
    float hf[32];
#pragma unroll
    for (int i = 0; i < 32; ++i) hf[i] = h[((size_t)(b * 32 + i) << 16) + pos];
    PIN32(hf);
    float res[3];
    for (int d = 0; d < 3; ++d) {
        float z1[32];
        const float* w1p = w1t + d * 1024;
#pragma unroll 4
        for (int o = 0; o < 32; ++o) {
            const float* wrow = w1p + o * 32;    // uniform -> s_load
            float a = b1[d * 32 + o];
#pragma unroll
            for (int i = 0; i < 32; ++i) a += hf[i] * wrow[i];
            z1[o] = gelu_f(a);
        }
        PIN32(z1);
        float z3 = b3[d];
        const float* w2p = w2t + d * 4096;
#pragma unroll 2
        for (int j = 0; j < 128; ++j) {
            const float* wrow = w2p + j * 32;    // uniform -> s_load
            float a = b2[d * 128 + j];
#pragma unroll
            for (int i = 0; i < 32; ++i) a += z1[i] * wrow[i];
            z3 += gelu_f(a) * w3[d * 128 + j];
        }
        res[d] = z3;
    }
    out[(size_t)g * 3 + 0] = res[0];
    out[(size_t)g * 3 + 1] = res[1];
    out[(size_t)g * 3 + 2] = res[2];
}

// ---------------------------------------------------------------------------
// Workspace (floats): gy and gi share one region (disjoint lifetimes).
// Total = 19,028,992 floats = 76.1 MB (proven safe in rounds 3-5).
// ---------------------------------------------------------------------------
extern "C" void kernel_launch(void* const* d_in, const int* in_sizes, int n_in,
                              void* d_out, int out_size, void* d_ws, size_t ws_size,
                              hipStream_t stream) {
    const float* bc      = (const float*)d_in[0];
    const float* xg      = (const float*)d_in[1];
    const float* yg      = (const float*)d_in[2];
    const float* mlp1_w  = (const float*)d_in[3];
    const float* mlp1_b  = (const float*)d_in[4];
    const float* spec_wr = (const float*)d_in[5];
    const float* spec_wi = (const float*)d_in[6];
    const float* pw_w    = (const float*)d_in[7];
    const float* pw_b    = (const float*)d_in[8];
    const float* dec_w1  = (const float*)d_in[9];
    const float* dec_b1  = (const float*)d_in[10];
    const float* dec_w2  = (const float*)d_in[11];
    const float* dec_b2  = (const float*)d_in[12];
    const float* dec_w3  = (const float*)d_in[13];
    const float* dec_b3  = (const float*)d_in[14];
    float* out = (float*)d_out;

    float* h    = (float*)d_ws;               // 16,777,216 floats
    float* spec = h + 16777216;               //  2,097,152 (shared gy / gi)
    float* Xf   = spec + 2097152;             //    131,072
    float* Wf   = Xf + 131072;                //      8,192
    float* w1t  = Wf + 8192;                  //      3,072
    float* w2t  = w1t + 3072;                 //     12,288
    float* gy   = spec;
    float* gi   = spec;
    (void)ws_size; (void)n_in; (void)in_sizes; (void)out_size;

    k_twiddle<<<32, 256, 0, stream>>>(Wf);
    k_prep_dec<<<1, 256, 0, stream>>>(dec_w1, dec_w2, w1t, w2t);
    k_lift<<<2048, 256, 0, stream>>>(bc, xg, yg, mlp1_w, mlp1_b, h);
    for (int l = 0; l < NL; ++l) {
        k_fwd_y<<<1024, 256, 0, stream>>>(h, Wf, gy);
        k_fwd_x<<<256, 1024, 0, stream>>>(gy, Xf);
        k_spec<<<256, 1024, 0, stream>>>(Xf, spec_wr + (size_t)l * 262144,
                                         spec_wi + (size_t)l * 262144, gi);
        k_update<<<2048, 256, 0, stream>>>(h, gi, pw_w + l * 1024, pw_b + l * 32);
    }
    k_decode<<<2048, 256, 0, stream>>>(h, w1t, dec_b1, w2t, dec_b2,
                                       dec_w3, dec_b3, out);
}

// Round 7
// 890.766 us; speedup vs baseline: 1.1112x; 1.1112x over previous
//
#include <hip/hip_runtime.h>
#include <math.h>

// Problem constants
#define BSZ 8
#define CW  32      // WIDTH (channels)
#define NN  256     // NX = NY
#define MM  16      // modes M1 = M2
#define NL  4
#define HID 128

typedef __attribute__((ext_vector_type(8))) short bf16x8;
typedef __attribute__((ext_vector_type(4))) float f32x4;
typedef __attribute__((ext_vector_type(4))) unsigned int u32x4;

// Anti-rematerialization pin (kept for k_update, known-good)
#define PIN4(a,b,c,d) asm volatile("" : "+v"(a), "+v"(b), "+v"(c), "+v"(d))
#define PIN32(A) do { \
    PIN4(A[0],A[1],A[2],A[3]);     PIN4(A[4],A[5],A[6],A[7]); \
    PIN4(A[8],A[9],A[10],A[11]);   PIN4(A[12],A[13],A[14],A[15]); \
    PIN4(A[16],A[17],A[18],A[19]); PIN4(A[20],A[21],A[22],A[23]); \
    PIN4(A[24],A[25],A[26],A[27]); PIN4(A[28],A[29],A[30],A[31]); \
} while (0)
#define PIN16(A) do { \
    PIN4(A[0],A[1],A[2],A[3]);     PIN4(A[4],A[5],A[6],A[7]); \
    PIN4(A[8],A[9],A[10],A[11]);   PIN4(A[12],A[13],A[14],A[15]); \
} while (0)

// ---------------------------------------------------------------------------
// Fast exact-erf GELU: Abramowitz-Stegun 7.1.26 (max |err| 1.5e-7), branchless.
// ---------------------------------------------------------------------------
static __device__ __forceinline__ float gelu_f(float v) {
    float au = fabsf(v) * 0.70710678118654752f;
    float t  = __builtin_amdgcn_rcpf(fmaf(0.3275911f, au, 1.0f));
    float p  = fmaf(fmaf(fmaf(fmaf(1.061405429f, t, -1.453152027f),
                              t, 1.421413741f),
                         t, -0.284496736f),
                    t, 0.254829592f) * t;
    float e  = __expf(-au * au);
    float E  = fmaf(-p, e, 1.0f);          // erf(|v|/sqrt2)
    return fmaf(0.5f * fabsf(v), E, 0.5f * v);
}

// fp32 -> (bf16 hi | bf16 lo) packed u32, truncation split: v ~= hi + lo exactly
// to ~2^-16 relative.
static __device__ __forceinline__ unsigned pack_hl(float v) {
    unsigned b  = __float_as_uint(v);
    unsigned hi = b >> 16;
    float hif   = __uint_as_float(hi << 16);
    float lo    = v - hif;
    unsigned lou = __float_as_uint(lo) >> 16;
    return (hi << 16) | lou;
}

#define TWO_PI_OVER_N (6.28318530717958647692f / 256.0f)

// ---------------------------------------------------------------------------
// Build forward-DFT twiddle matrix Wf[y][2*ky+p]: p=0 -> cos, p=1 -> -sin
// ---------------------------------------------------------------------------
__global__ void k_twiddle(float* __restrict__ Wf) {
    int idx = blockIdx.x * 256 + threadIdx.x;   // 8192 = 256 y * 32 c
    int y = idx >> 5, c = idx & 31;
    int ky = c >> 1, p = c & 1;
    int m = (ky * y) & 255;
    float ang = (float)m * TWO_PI_OVER_N;
    Wf[idx] = p ? -sinf(ang) : cosf(ang);
}

// ---------------------------------------------------------------------------
// Pack decoder weights into MFMA-B-frag-friendly layout (bf16 hi|lo in u32):
// wb1p[((d*2+nb)*16+n)*32+k]  <- dec_w1[d][k][nb*16+n]   (3*2*16*32 = 3072)
// wb2p[((d*8+blk)*16+n)*32+k] <- dec_w2[d][k][blk*16+n]  (3*8*16*32 = 12288)
// ---------------------------------------------------------------------------
__global__ void k_prep_dec(const float* __restrict__ w1, const float* __restrict__ w2,
                           unsigned* __restrict__ wb1p, unsigned* __restrict__ wb2p) {
    int tid = threadIdx.x;
    for (int idx = tid; idx < 3 * 2 * 16 * 32; idx += 256) {
        int k = idx & 31, n16 = (idx >> 5) & 15, nb = (idx >> 9) & 1, d = idx >> 10;
        wb1p[idx] = pack_hl(w1[d * 1024 + k * 32 + nb * 16 + n16]);
    }
    for (int idx = tid; idx < 3 * 8 * 16 * 32; idx += 256) {
        int k = idx & 31, n16 = (idx >> 5) & 15, blk = (idx >> 9) & 7, d = idx >> 12;
        wb2p[idx] = pack_hl(w2[d * 4096 + k * 128 + blk * 16 + n16]);
    }
}

// ---------------------------------------------------------------------------
// Lifting
// ---------------------------------------------------------------------------
__global__ void k_lift(const float* __restrict__ bc, const float* __restrict__ xg,
                       const float* __restrict__ yg, const float* __restrict__ w,
                       const float* __restrict__ bias, float* __restrict__ h) {
    int idx = blockIdx.x * 256 + threadIdx.x;   // over B*N*N
    int b = idx >> 16, pos = idx & 65535;
    float i0 = bc[b * 3 + 0], i1 = bc[b * 3 + 1], i2 = bc[b * 3 + 2];
    float i3 = xg[idx], i4 = yg[idx];
#pragma unroll
    for (int c = 0; c < CW; ++c) {
        float v = i0 * w[c] + i1 * w[CW + c] + i2 * w[2 * CW + c]
                + i3 * w[3 * CW + c] + i4 * w[4 * CW + c] + bias[c];
        h[((size_t)(b * CW + c) << 16) + pos] = v;
    }
}

// ---------------------------------------------------------------------------
// Forward DFT along y as GEMM vs Wf. 4 waves; wave wv owns y-quarter,
// lane l owns row blockIdx*64+l. Wf wave-uniform -> s_load. LDS reduce.
// ---------------------------------------------------------------------------
__global__ void k_fwd_y(const float* __restrict__ h, const float* __restrict__ Wf,
                        float* __restrict__ gy) {
    __shared__ float red[4][64][33];   // padded
    int tid = threadIdx.x;
    int wv = tid >> 6, lane = tid & 63;
    int row0 = blockIdx.x * 64;
    const float* hp = h + (size_t)(row0 + lane) * 256 + wv * 64;
    const float* wp = Wf + wv * 64 * 32;
    float acc[32];
#pragma unroll
    for (int c = 0; c < 32; ++c) acc[c] = 0.f;
#pragma unroll 4
    for (int yy = 0; yy < 64; yy += 4) {
        float4 hv = *(const float4*)(hp + yy);
        const float* wr0 = wp + yy * 32;
#pragma unroll
        for (int c = 0; c < 32; ++c) acc[c] += hv.x * wr0[c];
#pragma unroll
        for (int c = 0; c < 32; ++c) acc[c] += hv.y * wr0[32 + c];
#pragma unroll
        for (int c = 0; c < 32; ++c) acc[c] += hv.z * wr0[64 + c];
#pragma unroll
        for (int c = 0; c < 32; ++c) acc[c] += hv.w * wr0[96 + c];
    }
#pragma unroll
    for (int c = 0; c < 32; ++c) red[wv][lane][c] = acc[c];
    __syncthreads();
#pragma unroll
    for (int k = 0; k < 8; ++k) {
        int o = k * 256 + tid;          // 0..2047
        int r = o >> 5, c = o & 31;
        float v = red[0][r][c] + red[1][r][c] + red[2][r][c] + red[3][r][c];
        gy[(size_t)(row0 + r) * 32 + c] = v;
    }
}

// ---------------------------------------------------------------------------
// Forward DFT along x, 1024 threads (split-K + LDS reduce)
// ---------------------------------------------------------------------------
__global__ void __launch_bounds__(1024) k_fwd_x(const float* __restrict__ gy,
                                                float* __restrict__ Xf) {
    __shared__ float g[8192];           // (x, c) 32 KB
    __shared__ float part[4][256][2];   // 8 KB
    __shared__ float ct[256], st[256];
    int tid = threadIdx.x;
    if (tid < 256) {
        float ang = (float)tid * TWO_PI_OVER_N;
        ct[tid] = cosf(ang);
        st[tid] = sinf(ang);
    }
    size_t base = (size_t)blockIdx.x * 8192;
#pragma unroll
    for (int j = 0; j < 8; ++j) g[j * 1024 + tid] = gy[base + j * 1024 + tid];
    __syncthreads();

    int t = tid & 255, xq = tid >> 8;
    int kx = t >> 4, ky = t & 15;
    float ar = 0.f, ai = 0.f;
    int x0 = xq * 64;
    int idx = (kx * x0) & 255;
#pragma unroll 4
    for (int x = x0; x < x0 + 64; ++x) {
        float c = ct[idx], s = st[idx];
        float gr = g[x * 32 + ky * 2], gi = g[x * 32 + ky * 2 + 1];
        ar += gr * c + gi * s;          // e^{-i}
        ai += gi * c - gr * s;
        idx = (idx + kx) & 255;
    }
    part[xq][t][0] = ar;
    part[xq][t][1] = ai;
    __syncthreads();
    if (tid < 256) {
        float a0 = part[0][tid][0] + part[1][tid][0] + part[2][tid][0] + part[3][tid][0];
        float a1 = part[0][tid][1] + part[1][tid][1] + part[2][tid][1] + part[3][tid][1];
        Xf[((size_t)blockIdx.x * 256 + tid) * 2 + 0] = a0 * (1.0f / 256.0f);
        Xf[((size_t)blockIdx.x * 256 + tid) * 2 + 1] = a1 * (1.0f / 256.0f);
    }
}

// ---------------------------------------------------------------------------
// Fused mode-mix + inverse x-DFT, 1024 threads. Block = (b,o), grid 256.
// ---------------------------------------------------------------------------
__global__ void __launch_bounds__(1024) k_spec(const float* __restrict__ Xf,
                                               const float* __restrict__ wr,
                                               const float* __restrict__ wi,
                                               float* __restrict__ gi) {
    __shared__ float tl[512];
    __shared__ float pp[4][256][2];
    __shared__ float ct[256], st[256];
    int tid = threadIdx.x;
    if (tid < 256) {
        float ang = (float)tid * TWO_PI_OVER_N;
        ct[tid] = cosf(ang);
        st[tid] = sinf(ang);
    }
    int b = blockIdx.x >> 5, o = blockIdx.x & 31;
    int t = tid & 255, ig = tid >> 8;

    // phase 1: mix (split-K over i)
    float tr = 0.f, ti = 0.f;
    const float2* xp = (const float2*)Xf + (size_t)b * 8192 + t;
    const float* wrp = wr + (size_t)o * 256 + t;
    const float* wip = wi + (size_t)o * 256 + t;
#pragma unroll
    for (int i = ig * 8; i < ig * 8 + 8; ++i) {
        float2 xv = xp[i * 256];
        float wrv = wrp[(size_t)i * 8192];
        float wiv = wip[(size_t)i * 8192];
        tr += xv.x * wrv - xv.y * wiv;
        ti += xv.x * wiv + xv.y * wrv;
    }
    pp[ig][t][0] = tr;
    pp[ig][t][1] = ti;
    __syncthreads();
    if (tid < 256) {
        tl[tid * 2 + 0] = pp[0][tid][0] + pp[1][tid][0] + pp[2][tid][0] + pp[3][tid][0];
        tl[tid * 2 + 1] = pp[0][tid][1] + pp[1][tid][1] + pp[2][tid][1] + pp[3][tid][1];
    }
    __syncthreads();

    // phase 2: inverse x-DFT; thread handles 4 ky for one x
    int x = t, kg = ig;
    float gre[4], gim[4];
#pragma unroll
    for (int k = 0; k < 4; ++k) { gre[k] = 0.f; gim[k] = 0.f; }
#pragma unroll 4
    for (int kx = 0; kx < 16; ++kx) {
        int idx = (kx * x) & 255;
        float c = ct[idx], s = st[idx];
#pragma unroll
        for (int k = 0; k < 4; ++k) {
            int ky = kg * 4 + k;
            float t2r = tl[(kx * 16 + ky) * 2 + 0];
            float t2i = tl[(kx * 16 + ky) * 2 + 1];
            gre[k] += t2r * c - t2i * s;   // e^{+i}
            gim[k] += t2i * c + t2r * s;
        }
    }
    size_t ob = (((size_t)b * 256 + x) * 32 + o) * 32;
#pragma unroll
    for (int k = 0; k < 4; ++k) {
        gi[ob + (kg * 4 + k) * 2 + 0] = gre[k];
        gi[ob + (kg * 4 + k) * 2 + 1] = gim[k];
    }
}

// ---------------------------------------------------------------------------
// Fused inverse-y DFT (c2r) + pointwise + GELU + residual (unchanged, passing)
// ---------------------------------------------------------------------------
__global__ void __launch_bounds__(256, 4) k_update(float* __restrict__ h,
                         const float* __restrict__ gi,
                         const float* __restrict__ pww, const float* __restrict__ pwb) {
    __shared__ float ct[256], st[256];
    int tid = threadIdx.x;
    int bx = blockIdx.x;               // b*256 + x
    int b = bx >> 8, x = bx & 255;
    {
        float ang = (float)tid * TWO_PI_OVER_N;
        ct[tid] = cosf(ang);
        st[tid] = sinf(ang);
    }
    __syncthreads();

    int y = tid;
    size_t hbase = ((size_t)b * 32) << 16;
    float hv[32];
#pragma unroll
    for (int i = 0; i < 32; ++i) hv[i] = h[hbase + ((size_t)i << 16) + x * 256 + y];
    PIN32(hv);
    float cy[16], sy[16];
#pragma unroll
    for (int ky = 0; ky < 16; ++ky) {
        int m = (ky * y) & 255;
        cy[ky] = ct[m];
        sy[ky] = st[m];
    }
    PIN16(cy);
    PIN16(sy);
    const float* gp = gi + (size_t)bx * 1024;
#pragma unroll 4
    for (int o = 0; o < 32; ++o) {
        const float* go = gp + o * 32;       // uniform -> s_load
        float sc = 0.5f * go[0];             // cy[0]=1, sy[0]=0
#pragma unroll
        for (int ky = 1; ky < 16; ++ky)
            sc += go[ky * 2] * cy[ky] - go[ky * 2 + 1] * sy[ky];
        sc *= (2.0f / 256.0f);
        const float* wo = pww + o * 32;      // uniform -> s_load
        float pw = pwb[o];
#pragma unroll
        for (int i = 0; i < 32; ++i) pw += hv[i] * wo[i];
        float u = sc + pw;
        h[hbase + ((size_t)o << 16) + x * 256 + y] = hv[o] + gelu_f(u);
    }
}

// ---------------------------------------------------------------------------
// MFMA decoder. Block = 256 thr = 4 waves; block owns 256 points of one b.
// Wave owns 64 points = 4 m-tiles of mfma_f32_16x16x32_bf16.
// bf16 hi/lo split (3 MFMA passes) for fp32-like precision.
// Layer1: A = h (global, frag-layout loads, cvt once, reused for 3 heads)
// Z1 D-layout -> A-layout via per-wave XOR-swizzled LDS (no barriers).
// Layer2: 8 n-blocks MFMA. Layer3 (K=128,N=1): vector + shfl_xor butterfly.
// Frag layouts (gfx950, verified m89/m91): A: lane l -> A[l&15][(l>>4)*8+j];
// B: lane l -> B[(l>>4)*8+j][l&15]; D: lane l,reg r -> D[(l>>4)*4+r][l&15].
// ---------------------------------------------------------------------------
__global__ void __launch_bounds__(256) k_decode(const float* __restrict__ h,
        const unsigned* __restrict__ wb1p, const float* __restrict__ b1,
        const unsigned* __restrict__ wb2p, const float* __restrict__ b2,
        const float* __restrict__ w3, const float* __restrict__ b3,
        float* __restrict__ out) {
    __shared__ unsigned z1s[4][64][32];     // per-wave [rw][c], XOR-swizzled 16B slots
    int tid = threadIdx.x;
    int wv = tid >> 6, l = tid & 63;
    int l15 = l & 15, lk = l >> 4;          // lk = k/row group
    int b = blockIdx.x >> 8;
    int pos0 = (blockIdx.x & 255) * 256;

    // ---- stage A-frags for layer1 (reused across 3 heads) ----
    bf16x8 ah[4], al[4];
    const float* hb = h + (((size_t)b * 32) << 16) + pos0;
#pragma unroll
    for (int mt = 0; mt < 4; ++mt) {
        int p = wv * 64 + mt * 16 + l15;
#pragma unroll
        for (int j = 0; j < 8; ++j) {
            float v = hb[((size_t)(lk * 8 + j) << 16) + p];
            unsigned pb = pack_hl(v);
            ah[mt][j] = (short)(pb >> 16);
            al[mt][j] = (short)(pb & 0xffffu);
        }
    }

    size_t gbase = (size_t)blockIdx.x * 256 + wv * 64;
    for (int d = 0; d < 3; ++d) {
        float b3d = b3[d];
#pragma unroll
        for (int mt = 0; mt < 4; ++mt) {
            // ---- layer 1: two 16-col blocks ----
#pragma unroll
            for (int nb = 0; nb < 2; ++nb) {
                const unsigned* wp = wb1p + (((d * 2 + nb) * 16 + l15) * 32 + lk * 8);
                u32x4 w0 = *(const u32x4*)wp;
                u32x4 w1v = *(const u32x4*)(wp + 4);
                bf16x8 bh, bl2;
#pragma unroll
                for (int j = 0; j < 4; ++j) {
                    bh[j]     = (short)(w0[j] >> 16);
                    bl2[j]    = (short)(w0[j] & 0xffffu);
                    bh[4 + j] = (short)(w1v[j] >> 16);
                    bl2[4 + j] = (short)(w1v[j] & 0xffffu);
                }
                f32x4 acc = {0.f, 0.f, 0.f, 0.f};
                acc = __builtin_amdgcn_mfma_f32_16x16x32_bf16(al[mt], bh, acc, 0, 0, 0);
                acc = __builtin_amdgcn_mfma_f32_16x16x32_bf16(ah[mt], bl2, acc, 0, 0, 0);
                acc = __builtin_amdgcn_mfma_f32_16x16x32_bf16(ah[mt], bh, acc, 0, 0, 0);
                float bias = b1[d * 32 + nb * 16 + l15];
                int c = nb * 16 + l15;
#pragma unroll
                for (int r = 0; r < 4; ++r) {
                    float z = gelu_f(acc[r] + bias);
                    int rw = mt * 16 + lk * 4 + r;
                    z1s[wv][rw][(((c >> 2) ^ (rw & 7)) << 2) | (c & 3)] = pack_hl(z);
                }
            }
            // ---- layer 2: read z1 A-frags back (within-wave dep, lgkmcnt) ----
            int rwr = mt * 16 + l15;
            int sl0 = (2 * lk) ^ (rwr & 7);
            int sl1 = (2 * lk + 1) ^ (rwr & 7);
            u32x4 q0 = *(const u32x4*)&z1s[wv][rwr][sl0 << 2];
            u32x4 q1 = *(const u32x4*)&z1s[wv][rwr][sl1 << 2];
            bf16x8 zah, zal;
#pragma unroll
            for (int j = 0; j < 4; ++j) {
                zah[j]     = (short)(q0[j] >> 16);
                zal[j]     = (short)(q0[j] & 0xffffu);
                zah[4 + j] = (short)(q1[j] >> 16);
                zal[4 + j] = (short)(q1[j] & 0xffffu);
            }
            float p3[4] = {0.f, 0.f, 0.f, 0.f};
#pragma unroll
            for (int blk = 0; blk < 8; ++blk) {
                const unsigned* wp = wb2p + (((d * 8 + blk) * 16 + l15) * 32 + lk * 8);
                u32x4 w0 = *(const u32x4*)wp;
                u32x4 w1v = *(const u32x4*)(wp + 4);
                bf16x8 bh, bl2;
#pragma unroll
                for (int j = 0; j < 4; ++j) {
                    bh[j]     = (short)(w0[j] >> 16);
                    bl2[j]    = (short)(w0[j] & 0xffffu);
                    bh[4 + j] = (short)(w1v[j] >> 16);
                    bl2[4 + j] = (short)(w1v[j] & 0xffffu);
                }
                f32x4 acc = {0.f, 0.f, 0.f, 0.f};
                acc = __builtin_amdgcn_mfma_f32_16x16x32_bf16(zal, bh, acc, 0, 0, 0);
                acc = __builtin_amdgcn_mfma_f32_16x16x32_bf16(zah, bl2, acc, 0, 0, 0);
                acc = __builtin_amdgcn_mfma_f32_16x16x32_bf16(zah, bh, acc, 0, 0, 0);
                float bias = b2[d * 128 + blk * 16 + l15];
                float w3v  = w3[d * 128 + blk * 16 + l15];
#pragma unroll
                for (int r = 0; r < 4; ++r)
                    p3[r] = fmaf(gelu_f(acc[r] + bias), w3v, p3[r]);
            }
            // ---- layer 3 reduce over the 16 n-lanes ----
#pragma unroll
            for (int r = 0; r < 4; ++r) {
                p3[r] += __shfl_xor(p3[r], 1, 64);
                p3[r] += __shfl_xor(p3[r], 2, 64);
                p3[r] += __shfl_xor(p3[r], 4, 64);
                p3[r] += __shfl_xor(p3[r], 8, 64);
            }
#pragma unroll
            for (int r = 0; r < 4; ++r) {
                if (l15 == r)
                    out[(gbase + mt * 16 + lk * 4 + r) * 3 + d] = p3[r] + b3d;
            }
        }
    }
}

// ---------------------------------------------------------------------------
// Workspace (floats): gy and gi share one region (disjoint lifetimes).
// Total = 19,028,992 floats = 76.1 MB (proven safe rounds 3-6).
// ---------------------------------------------------------------------------
extern "C" void kernel_launch(void* const* d_in, const int* in_sizes, int n_in,
                              void* d_out, int out_size, void* d_ws, size_t ws_size,
                              hipStream_t stream) {
    const float* bc      = (const float*)d_in[0];
    const float* xg      = (const float*)d_in[1];
    const float* yg      = (const float*)d_in[2];
    const float* mlp1_w  = (const float*)d_in[3];
    const float* mlp1_b  = (const float*)d_in[4];
    const float* spec_wr = (const float*)d_in[5];
    const float* spec_wi = (const float*)d_in[6];
    const float* pw_w    = (const float*)d_in[7];
    const float* pw_b    = (const float*)d_in[8];
    const float* dec_w1  = (const float*)d_in[9];
    const float* dec_b1  = (const float*)d_in[10];
    const float* dec_w2  = (const float*)d_in[11];
    const float* dec_b2  = (const float*)d_in[12];
    const float* dec_w3  = (const float*)d_in[13];
    const float* dec_b3  = (const float*)d_in[14];
    float* out = (float*)d_out;

    float* h    = (float*)d_ws;               // 16,777,216 floats
    float* spec = h + 16777216;               //  2,097,152 (shared gy / gi)
    float* Xf   = spec + 2097152;             //    131,072
    float* Wf   = Xf + 131072;                //      8,192
    unsigned* wb1p = (unsigned*)(Wf + 8192);  //      3,072
    unsigned* wb2p = wb1p + 3072;             //     12,288
    float* gy   = spec;
    float* gi   = spec;
    (void)ws_size; (void)n_in; (void)in_sizes; (void)out_size;

    k_twiddle<<<32, 256, 0, stream>>>(Wf);
    k_prep_dec<<<1, 256, 0, stream>>>(dec_w1, dec_w2, wb1p, wb2p);
    k_lift<<<2048, 256, 0, stream>>>(bc, xg, yg, mlp1_w, mlp1_b, h);
    for (int l = 0; l < NL; ++l) {
        k_fwd_y<<<1024, 256, 0, stream>>>(h, Wf, gy);
        k_fwd_x<<<256, 1024, 0, stream>>>(gy, Xf);
        k_spec<<<256, 1024, 0, stream>>>(Xf, spec_wr + (size_t)l * 262144,
                                         spec_wi + (size_t)l * 262144, gi);
        k_update<<<2048, 256, 0, stream>>>(h, gi, pw_w + l * 1024, pw_b + l * 32);
    }
    k_decode<<<2048, 256, 0, stream>>>(h, wb1p, dec_b1, wb2p, dec_b2,
                                       dec_w3, dec_b3, out);
}

// Round 8
// 850.475 us; speedup vs baseline: 1.1638x; 1.0474x over previous
//
#include <hip/hip_runtime.h>
#include <math.h>

// Problem constants
#define BSZ 8
#define CW  32      // WIDTH (channels)
#define NN  256     // NX = NY
#define MM  16      // modes M1 = M2
#define NL  4
#define HID 128

typedef __attribute__((ext_vector_type(8))) short bf16x8;
typedef __attribute__((ext_vector_type(4))) float f32x4;
typedef __attribute__((ext_vector_type(4))) unsigned int u32x4;

// Anti-rematerialization pin (k_update, known-good)
#define PIN4(a,b,c,d) asm volatile("" : "+v"(a), "+v"(b), "+v"(c), "+v"(d))
#define PIN32(A) do { \
    PIN4(A[0],A[1],A[2],A[3]);     PIN4(A[4],A[5],A[6],A[7]); \
    PIN4(A[8],A[9],A[10],A[11]);   PIN4(A[12],A[13],A[14],A[15]); \
    PIN4(A[16],A[17],A[18],A[19]); PIN4(A[20],A[21],A[22],A[23]); \
    PIN4(A[24],A[25],A[26],A[27]); PIN4(A[28],A[29],A[30],A[31]); \
} while (0)
#define PIN16(A) do { \
    PIN4(A[0],A[1],A[2],A[3]);     PIN4(A[4],A[5],A[6],A[7]); \
    PIN4(A[8],A[9],A[10],A[11]);   PIN4(A[12],A[13],A[14],A[15]); \
} while (0)

// ---------------------------------------------------------------------------
// Fast exact-erf GELU: Abramowitz-Stegun 7.1.26 (max |err| 1.5e-7), branchless.
// ---------------------------------------------------------------------------
static __device__ __forceinline__ float gelu_f(float v) {
    float au = fabsf(v) * 0.70710678118654752f;
    float t  = __builtin_amdgcn_rcpf(fmaf(0.3275911f, au, 1.0f));
    float p  = fmaf(fmaf(fmaf(fmaf(1.061405429f, t, -1.453152027f),
                              t, 1.421413741f),
                         t, -0.284496736f),
                    t, 0.254829592f) * t;
    float e  = __expf(-au * au);
    float E  = fmaf(-p, e, 1.0f);          // erf(|v|/sqrt2)
    return fmaf(0.5f * fabsf(v), E, 0.5f * v);
}

// fp32 -> (bf16 hi | bf16 lo) packed u32, truncation split
static __device__ __forceinline__ unsigned pack_hl(float v) {
    unsigned b  = __float_as_uint(v);
    unsigned hi = b >> 16;
    float hif   = __uint_as_float(hi << 16);
    float lo    = v - hif;
    unsigned lou = __float_as_uint(lo) >> 16;
    return (hi << 16) | lou;
}

#define TWO_PI_OVER_N (6.28318530717958647692f / 256.0f)

// ---------------------------------------------------------------------------
// Build forward-DFT twiddle matrix Wf[y][2*ky+p]: p=0 -> cos, p=1 -> -sin
// ---------------------------------------------------------------------------
__global__ void k_twiddle(float* __restrict__ Wf) {
    int idx = blockIdx.x * 256 + threadIdx.x;   // 8192 = 256 y * 32 c
    int y = idx >> 5, c = idx & 31;
    int ky = c >> 1, p = c & 1;
    int m = (ky * y) & 255;
    float ang = (float)m * TWO_PI_OVER_N;
    Wf[idx] = p ? -sinf(ang) : cosf(ang);
}

// ---------------------------------------------------------------------------
// Pack decoder weights into MFMA-B-frag layout (bf16 hi|lo in u32)
// ---------------------------------------------------------------------------
__global__ void k_prep_dec(const float* __restrict__ w1, const float* __restrict__ w2,
                           unsigned* __restrict__ wb1p, unsigned* __restrict__ wb2p) {
    int tid = threadIdx.x;
    for (int idx = tid; idx < 3 * 2 * 16 * 32; idx += 256) {
        int k = idx & 31, n16 = (idx >> 5) & 15, nb = (idx >> 9) & 1, d = idx >> 10;
        wb1p[idx] = pack_hl(w1[d * 1024 + k * 32 + nb * 16 + n16]);
    }
    for (int idx = tid; idx < 3 * 8 * 16 * 32; idx += 256) {
        int k = idx & 31, n16 = (idx >> 5) & 15, blk = (idx >> 9) & 7, d = idx >> 12;
        wb2p[idx] = pack_hl(w2[d * 4096 + k * 128 + blk * 16 + n16]);
    }
}

// ---------------------------------------------------------------------------
// Lifting
// ---------------------------------------------------------------------------
__global__ void k_lift(const float* __restrict__ bc, const float* __restrict__ xg,
                       const float* __restrict__ yg, const float* __restrict__ w,
                       const float* __restrict__ bias, float* __restrict__ h) {
    int idx = blockIdx.x * 256 + threadIdx.x;   // over B*N*N
    int b = idx >> 16, pos = idx & 65535;
    float i0 = bc[b * 3 + 0], i1 = bc[b * 3 + 1], i2 = bc[b * 3 + 2];
    float i3 = xg[idx], i4 = yg[idx];
#pragma unroll
    for (int c = 0; c < CW; ++c) {
        float v = i0 * w[c] + i1 * w[CW + c] + i2 * w[2 * CW + c]
                + i3 * w[3 * CW + c] + i4 * w[4 * CW + c] + bias[c];
        h[((size_t)(b * CW + c) << 16) + pos] = v;
    }
}

// ---------------------------------------------------------------------------
// Forward DFT along y. h tile (64 rows x 256) staged through LDS with
// COALESCED global loads (thread=y), XOR-swizzled to keep b32 reads 2-way.
// Compute: lane owns row, wave owns y-quarter; Wf rows via s_load (uniform);
// 32 register accs. Reduce buffer unioned into the same 64 KB LDS.
// ---------------------------------------------------------------------------
__global__ void k_fwd_y(const float* __restrict__ h, const float* __restrict__ Wf,
                        float* __restrict__ gy) {
    __shared__ float smem[16384];      // tile[64][256] (swizzled)  ∪  red[4][64][33]
    int tid = threadIdx.x;
    int wv = tid >> 6, lane = tid & 63;
    int row0 = blockIdx.x * 64;
    const float* hp = h + (size_t)row0 * 256;
#pragma unroll 8
    for (int k = 0; k < 64; ++k)       // row k, y = tid  (coalesced)
        smem[k * 256 + (tid ^ (k & 31))] = hp[k * 256 + tid];
    __syncthreads();

    const float* wp = Wf + wv * 64 * 32;
    const float* trow = &smem[lane * 256];
    int swz = lane & 31;
    float acc[32];
#pragma unroll
    for (int c = 0; c < 32; ++c) acc[c] = 0.f;
#pragma unroll 4
    for (int yy = 0; yy < 64; ++yy) {
        float hv = trow[(wv * 64 + yy) ^ swz];
        const float* wr0 = wp + yy * 32;        // wave-uniform -> s_load
#pragma unroll
        for (int c = 0; c < 32; ++c) acc[c] += hv * wr0[c];
    }
    __syncthreads();                    // tile dead; reuse LDS as red
    float (*red)[64][33] = (float(*)[64][33])smem;
#pragma unroll
    for (int c = 0; c < 32; ++c) red[wv][lane][c] = acc[c];
    __syncthreads();
#pragma unroll
    for (int k = 0; k < 8; ++k) {
        int o = k * 256 + tid;          // 0..2047
        int r = o >> 5, c = o & 31;
        float v = red[0][r][c] + red[1][r][c] + red[2][r][c] + red[3][r][c];
        gy[(size_t)(row0 + r) * 32 + c] = v;
    }
}

// ---------------------------------------------------------------------------
// Forward DFT along x, 1024 threads (split-K + LDS reduce)
// ---------------------------------------------------------------------------
__global__ void __launch_bounds__(1024) k_fwd_x(const float* __restrict__ gy,
                                                float* __restrict__ Xf) {
    __shared__ float g[8192];           // (x, c) 32 KB
    __shared__ float part[4][256][2];   // 8 KB
    __shared__ float ct[256], st[256];
    int tid = threadIdx.x;
    if (tid < 256) {
        float ang = (float)tid * TWO_PI_OVER_N;
        ct[tid] = cosf(ang);
        st[tid] = sinf(ang);
    }
    size_t base = (size_t)blockIdx.x * 8192;
#pragma unroll
    for (int j = 0; j < 8; ++j) g[j * 1024 + tid] = gy[base + j * 1024 + tid];
    __syncthreads();

    int t = tid & 255, xq = tid >> 8;
    int kx = t >> 4, ky = t & 15;
    float ar = 0.f, ai = 0.f;
    int x0 = xq * 64;
    int idx = (kx * x0) & 255;
#pragma unroll 4
    for (int x = x0; x < x0 + 64; ++x) {
        float c = ct[idx], s = st[idx];
        float gr = g[x * 32 + ky * 2], gi = g[x * 32 + ky * 2 + 1];
        ar += gr * c + gi * s;          // e^{-i}
        ai += gi * c - gr * s;
        idx = (idx + kx) & 255;
    }
    part[xq][t][0] = ar;
    part[xq][t][1] = ai;
    __syncthreads();
    if (tid < 256) {
        float a0 = part[0][tid][0] + part[1][tid][0] + part[2][tid][0] + part[3][tid][0];
        float a1 = part[0][tid][1] + part[1][tid][1] + part[2][tid][1] + part[3][tid][1];
        Xf[((size_t)blockIdx.x * 256 + tid) * 2 + 0] = a0 * (1.0f / 256.0f);
        Xf[((size_t)blockIdx.x * 256 + tid) * 2 + 1] = a1 * (1.0f / 256.0f);
    }
}

// ---------------------------------------------------------------------------
// Fused mode-mix + inverse x-DFT, 1024 threads. Block = (b,o), grid 256.
// ---------------------------------------------------------------------------
__global__ void __launch_bounds__(1024) k_spec(const float* __restrict__ Xf,
                                               const float* __restrict__ wr,
                                               const float* __restrict__ wi,
                                               float* __restrict__ gi) {
    __shared__ float tl[512];
    __shared__ float pp[4][256][2];
    __shared__ float ct[256], st[256];
    int tid = threadIdx.x;
    if (tid < 256) {
        float ang = (float)tid * TWO_PI_OVER_N;
        ct[tid] = cosf(ang);
        st[tid] = sinf(ang);
    }
    int b = blockIdx.x >> 5, o = blockIdx.x & 31;
    int t = tid & 255, ig = tid >> 8;

    // phase 1: mix (split-K over i)
    float tr = 0.f, ti = 0.f;
    const float2* xp = (const float2*)Xf + (size_t)b * 8192 + t;
    const float* wrp = wr + (size_t)o * 256 + t;
    const float* wip = wi + (size_t)o * 256 + t;
#pragma unroll
    for (int i = ig * 8; i < ig * 8 + 8; ++i) {
        float2 xv = xp[i * 256];
        float wrv = wrp[(size_t)i * 8192];
        float wiv = wip[(size_t)i * 8192];
        tr += xv.x * wrv - xv.y * wiv;
        ti += xv.x * wiv + xv.y * wrv;
    }
    pp[ig][t][0] = tr;
    pp[ig][t][1] = ti;
    __syncthreads();
    if (tid < 256) {
        tl[tid * 2 + 0] = pp[0][tid][0] + pp[1][tid][0] + pp[2][tid][0] + pp[3][tid][0];
        tl[tid * 2 + 1] = pp[0][tid][1] + pp[1][tid][1] + pp[2][tid][1] + pp[3][tid][1];
    }
    __syncthreads();

    // phase 2: inverse x-DFT; thread handles 4 ky for one x
    int x = t, kg = ig;
    float gre[4], gim[4];
#pragma unroll
    for (int k = 0; k < 4; ++k) { gre[k] = 0.f; gim[k] = 0.f; }
#pragma unroll 4
    for (int kx = 0; kx < 16; ++kx) {
        int idx = (kx * x) & 255;
        float c = ct[idx], s = st[idx];
#pragma unroll
        for (int k = 0; k < 4; ++k) {
            int ky = kg * 4 + k;
            float t2r = tl[(kx * 16 + ky) * 2 + 0];
            float t2i = tl[(kx * 16 + ky) * 2 + 1];
            gre[k] += t2r * c - t2i * s;   // e^{+i}
            gim[k] += t2i * c + t2r * s;
        }
    }
    size_t ob = (((size_t)b * 256 + x) * 32 + o) * 32;
#pragma unroll
    for (int k = 0; k < 4; ++k) {
        gi[ob + (kg * 4 + k) * 2 + 0] = gre[k];
        gi[ob + (kg * 4 + k) * 2 + 1] = gim[k];
    }
}

// ---------------------------------------------------------------------------
// Fused inverse-y DFT (c2r) + pointwise + GELU + residual (unchanged, passing)
// ---------------------------------------------------------------------------
__global__ void __launch_bounds__(256, 4) k_update(float* __restrict__ h,
                         const float* __restrict__ gi,
                         const float* __restrict__ pww, const float* __restrict__ pwb) {
    __shared__ float ct[256], st[256];
    int tid = threadIdx.x;
    int bx = blockIdx.x;               // b*256 + x
    int b = bx >> 8, x = bx & 255;
    {
        float ang = (float)tid * TWO_PI_OVER_N;
        ct[tid] = cosf(ang);
        st[tid] = sinf(ang);
    }
    __syncthreads();

    int y = tid;
    size_t hbase = ((size_t)b * 32) << 16;
    float hv[32];
#pragma unroll
    for (int i = 0; i < 32; ++i) hv[i] = h[hbase + ((size_t)i << 16) + x * 256 + y];
    PIN32(hv);
    float cy[16], sy[16];
#pragma unroll
    for (int ky = 0; ky < 16; ++ky) {
        int m = (ky * y) & 255;
        cy[ky] = ct[m];
        sy[ky] = st[m];
    }
    PIN16(cy);
    PIN16(sy);
    const float* gp = gi + (size_t)bx * 1024;
#pragma unroll 4
    for (int o = 0; o < 32; ++o) {
        const float* go = gp + o * 32;       // uniform -> s_load
        float sc = 0.5f * go[0];             // cy[0]=1, sy[0]=0
#pragma unroll
        for (int ky = 1; ky < 16; ++ky)
            sc += go[ky * 2] * cy[ky] - go[ky * 2 + 1] * sy[ky];
        sc *= (2.0f / 256.0f);
        const float* wo = pww + o * 32;      // uniform -> s_load
        float pw = pwb[o];
#pragma unroll
        for (int i = 0; i < 32; ++i) pw += hv[i] * wo[i];
        float u = sc + pw;
        h[hbase + ((size_t)o << 16) + x * 256 + y] = hv[o] + gelu_f(u);
    }
}

// ---------------------------------------------------------------------------
// MFMA decoder, restructured: per head d -
//   preload+unpack w1 frags once -> layer1 for ALL 4 m-tiles -> z1 LDS
//   -> read 4 A-frags -> blk-OUTER layer2 (each w2 frag unpacked once,
//   feeds 4 m-tiles = 12 MFMAs) -> layer3 shfl reduce.
// Eliminates 4x-redundant weight unpack (~16% of VALU) and batches MFMAs.
// Frag layouts (verified passing round 7): A: lane l -> A[l&15][(l>>4)*8+j];
// B: lane l -> B[(l>>4)*8+j][l&15]; D: lane l,r -> D[(l>>4)*4+r][l&15].
// ---------------------------------------------------------------------------
__global__ void __launch_bounds__(256) k_decode(const float* __restrict__ h,
        const unsigned* __restrict__ wb1p, const float* __restrict__ b1,
        const unsigned* __restrict__ wb2p, const float* __restrict__ b2,
        const float* __restrict__ w3, const float* __restrict__ b3,
        float* __restrict__ out) {
    __shared__ unsigned z1s[4][64][32];     // per-wave, XOR-swizzled 16B slots
    int tid = threadIdx.x;
    int wv = tid >> 6, l = tid & 63;
    int l15 = l & 15, lk = l >> 4;
    int b = blockIdx.x >> 8;
    int pos0 = (blockIdx.x & 255) * 256;

    // stage A-frags for layer1 (reused across 3 heads)
    bf16x8 ah[4], al[4];
    const float* hb = h + (((size_t)b * 32) << 16) + pos0;
#pragma unroll
    for (int mt = 0; mt < 4; ++mt) {
        int p = wv * 64 + mt * 16 + l15;
#pragma unroll
        for (int j = 0; j < 8; ++j) {
            float v = hb[((size_t)(lk * 8 + j) << 16) + p];
            unsigned pb = pack_hl(v);
            ah[mt][j] = (short)(pb >> 16);
            al[mt][j] = (short)(pb & 0xffffu);
        }
    }

    size_t gbase = (size_t)blockIdx.x * 256 + wv * 64;
    for (int d = 0; d < 3; ++d) {
        // ---- preload layer-1 B-frags (unpack once per d) ----
        bf16x8 w1h[2], w1l[2];
        float bias1[2];
#pragma unroll
        for (int nb = 0; nb < 2; ++nb) {
            const unsigned* wp = wb1p + (((d * 2 + nb) * 16 + l15) * 32 + lk * 8);
            u32x4 w0 = *(const u32x4*)wp;
            u32x4 w1v = *(const u32x4*)(wp + 4);
#pragma unroll
            for (int j = 0; j < 4; ++j) {
                w1h[nb][j]     = (short)(w0[j] >> 16);
                w1l[nb][j]     = (short)(w0[j] & 0xffffu);
                w1h[nb][4 + j] = (short)(w1v[j] >> 16);
                w1l[nb][4 + j] = (short)(w1v[j] & 0xffffu);
            }
            bias1[nb] = b1[d * 32 + nb * 16 + l15];
        }
        // ---- phase 1: layer-1 for all 4 m-tiles, z1 -> LDS ----
#pragma unroll
        for (int mt = 0; mt < 4; ++mt) {
#pragma unroll
            for (int nb = 0; nb < 2; ++nb) {
                f32x4 acc = {0.f, 0.f, 0.f, 0.f};
                acc = __builtin_amdgcn_mfma_f32_16x16x32_bf16(al[mt], w1h[nb], acc, 0, 0, 0);
                acc = __builtin_amdgcn_mfma_f32_16x16x32_bf16(ah[mt], w1l[nb], acc, 0, 0, 0);
                acc = __builtin_amdgcn_mfma_f32_16x16x32_bf16(ah[mt], w1h[nb], acc, 0, 0, 0);
                int c = nb * 16 + l15;
#pragma unroll
                for (int r = 0; r < 4; ++r) {
                    float z = gelu_f(acc[r] + bias1[nb]);
                    int rw = mt * 16 + lk * 4 + r;
                    z1s[wv][rw][(((c >> 2) ^ (rw & 7)) << 2) | (c & 3)] = pack_hl(z);
                }
            }
        }
        // ---- read layer-2 A-frags for all 4 m-tiles (within-wave dep) ----
        bf16x8 zah[4], zal[4];
#pragma unroll
        for (int mt = 0; mt < 4; ++mt) {
            int rwr = mt * 16 + l15;
            int sl0 = (2 * lk) ^ (rwr & 7);
            int sl1 = (2 * lk + 1) ^ (rwr & 7);
            u32x4 q0 = *(const u32x4*)&z1s[wv][rwr][sl0 << 2];
            u32x4 q1 = *(const u32x4*)&z1s[wv][rwr][sl1 << 2];
#pragma unroll
            for (int j = 0; j < 4; ++j) {
                zah[mt][j]     = (short)(q0[j] >> 16);
                zal[mt][j]     = (short)(q0[j] & 0xffffu);
                zah[mt][4 + j] = (short)(q1[j] >> 16);
                zal[mt][4 + j] = (short)(q1[j] & 0xffffu);
            }
        }
        // ---- phase 2: blk outer (weights unpacked once), mt inner ----
        float p3[4][4];
#pragma unroll
        for (int mt = 0; mt < 4; ++mt)
#pragma unroll
            for (int r = 0; r < 4; ++r) p3[mt][r] = 0.f;
#pragma unroll 2
        for (int blk = 0; blk < 8; ++blk) {
            const unsigned* wp = wb2p + (((d * 8 + blk) * 16 + l15) * 32 + lk * 8);
            u32x4 w0 = *(const u32x4*)wp;
            u32x4 w1v = *(const u32x4*)(wp + 4);
            bf16x8 bh, bl2;
#pragma unroll
            for (int j = 0; j < 4; ++j) {
                bh[j]      = (short)(w0[j] >> 16);
                bl2[j]     = (short)(w0[j] & 0xffffu);
                bh[4 + j]  = (short)(w1v[j] >> 16);
                bl2[4 + j] = (short)(w1v[j] & 0xffffu);
            }
            float bias2 = b2[d * 128 + blk * 16 + l15];
            float w3v   = w3[d * 128 + blk * 16 + l15];
#pragma unroll
            for (int mt = 0; mt < 4; ++mt) {
                f32x4 acc = {0.f, 0.f, 0.f, 0.f};
                acc = __builtin_amdgcn_mfma_f32_16x16x32_bf16(zal[mt], bh, acc, 0, 0, 0);
                acc = __builtin_amdgcn_mfma_f32_16x16x32_bf16(zah[mt], bl2, acc, 0, 0, 0);
                acc = __builtin_amdgcn_mfma_f32_16x16x32_bf16(zah[mt], bh, acc, 0, 0, 0);
#pragma unroll
                for (int r = 0; r < 4; ++r)
                    p3[mt][r] = fmaf(gelu_f(acc[r] + bias2), w3v, p3[mt][r]);
            }
        }
        // ---- layer 3: reduce over the 16 n-lanes + store ----
        float b3d = b3[d];
#pragma unroll
        for (int mt = 0; mt < 4; ++mt) {
#pragma unroll
            for (int r = 0; r < 4; ++r) {
                float v = p3[mt][r];
                v += __shfl_xor(v, 1, 64);
                v += __shfl_xor(v, 2, 64);
                v += __shfl_xor(v, 4, 64);
                v += __shfl_xor(v, 8, 64);
                if (l15 == r)
                    out[(gbase + mt * 16 + lk * 4 + r) * 3 + d] = v + b3d;
            }
        }
    }
}

// ---------------------------------------------------------------------------
// Workspace (floats): gy and gi share one region (disjoint lifetimes).
// Total = 19,028,992 floats = 76.1 MB (proven safe rounds 3-7).
// ---------------------------------------------------------------------------
extern "C" void kernel_launch(void* const* d_in, const int* in_sizes, int n_in,
                              void* d_out, int out_size, void* d_ws, size_t ws_size,
                              hipStream_t stream) {
    const float* bc      = (const float*)d_in[0];
    const float* xg      = (const float*)d_in[1];
    const float* yg      = (const float*)d_in[2];
    const float* mlp1_w  = (const float*)d_in[3];
    const float* mlp1_b  = (const float*)d_in[4];
    const float* spec_wr = (const float*)d_in[5];
    const float* spec_wi = (const float*)d_in[6];
    const float* pw_w    = (const float*)d_in[7];
    const float* pw_b    = (const float*)d_in[8];
    const float* dec_w1  = (const float*)d_in[9];
    const float* dec_b1  = (const float*)d_in[10];
    const float* dec_w2  = (const float*)d_in[11];
    const float* dec_b2  = (const float*)d_in[12];
    const float* dec_w3  = (const float*)d_in[13];
    const float* dec_b3  = (const float*)d_in[14];
    float* out = (float*)d_out;

    float* h    = (float*)d_ws;               // 16,777,216 floats
    float* spec = h + 16777216;               //  2,097,152 (shared gy / gi)
    float* Xf   = spec + 2097152;             //    131,072
    float* Wf   = Xf + 131072;                //      8,192
    unsigned* wb1p = (unsigned*)(Wf + 8192);  //      3,072
    unsigned* wb2p = wb1p + 3072;             //     12,288
    float* gy   = spec;
    float* gi   = spec;
    (void)ws_size; (void)n_in; (void)in_sizes; (void)out_size;

    k_twiddle<<<32, 256, 0, stream>>>(Wf);
    k_prep_dec<<<1, 256, 0, stream>>>(dec_w1, dec_w2, wb1p, wb2p);
    k_lift<<<2048, 256, 0, stream>>>(bc, xg, yg, mlp1_w, mlp1_b, h);
    for (int l = 0; l < NL; ++l) {
        k_fwd_y<<<1024, 256, 0, stream>>>(h, Wf, gy);
        k_fwd_x<<<256, 1024, 0, stream>>>(gy, Xf);
        k_spec<<<256, 1024, 0, stream>>>(Xf, spec_wr + (size_t)l * 262144,
                                         spec_wi + (size_t)l * 262144, gi);
        k_update<<<2048, 256, 0, stream>>>(h, gi, pw_w + l * 1024, pw_b + l * 32);
    }
    k_decode<<<2048, 256, 0, stream>>>(h, wb1p, dec_b1, wb2p, dec_b2,
                                       dec_w3, dec_b3, out);
}

// Round 9
// 726.063 us; speedup vs baseline: 1.3632x; 1.1714x over previous
//
#include <hip/hip_runtime.h>
#include <math.h>

// Problem constants
#define BSZ 8
#define CW  32      // WIDTH (channels)
#define NN  256     // NX = NY
#define MM  16      // modes M1 = M2
#define NL  4
#define HID 128

typedef __attribute__((ext_vector_type(8))) short bf16x8;
typedef __attribute__((ext_vector_type(4))) float f32x4;
typedef __attribute__((ext_vector_type(4))) unsigned int u32x4;

// ---------------------------------------------------------------------------
// Fast exact-erf GELU: Abramowitz-Stegun 7.1.26 (max |err| 1.5e-7), branchless.
// ---------------------------------------------------------------------------
static __device__ __forceinline__ float gelu_f(float v) {
    float au = fabsf(v) * 0.70710678118654752f;
    float t  = __builtin_amdgcn_rcpf(fmaf(0.3275911f, au, 1.0f));
    float p  = fmaf(fmaf(fmaf(fmaf(1.061405429f, t, -1.453152027f),
                              t, 1.421413741f),
                         t, -0.284496736f),
                    t, 0.254829592f) * t;
    float e  = __expf(-au * au);
    float E  = fmaf(-p, e, 1.0f);          // erf(|v|/sqrt2)
    return fmaf(0.5f * fabsf(v), E, 0.5f * v);
}

// fp32 -> (bf16 hi | bf16 lo) packed u32, truncation split
static __device__ __forceinline__ unsigned pack_hl(float v) {
    unsigned b  = __float_as_uint(v);
    unsigned hi = b >> 16;
    float hif   = __uint_as_float(hi << 16);
    float lo    = v - hif;
    unsigned lou = __float_as_uint(lo) >> 16;
    return (hi << 16) | lou;
}

#define TWO_PI_OVER_N (6.28318530717958647692f / 256.0f)

// ---------------------------------------------------------------------------
// Build forward-DFT twiddle matrix Wf[y][2*ky+p]: p=0 -> cos, p=1 -> -sin
// ---------------------------------------------------------------------------
__global__ void k_twiddle(float* __restrict__ Wf) {
    int idx = blockIdx.x * 256 + threadIdx.x;   // 8192 = 256 y * 32 c
    int y = idx >> 5, c = idx & 31;
    int ky = c >> 1, p = c & 1;
    int m = (ky * y) & 255;
    float ang = (float)m * TWO_PI_OVER_N;
    Wf[idx] = p ? -sinf(ang) : cosf(ang);
}

// ---------------------------------------------------------------------------
// Prep: decoder weights in MFMA-B-frag layout (bf16 hi|lo u32);
// pw_w packed for update A-frags; Wi inverse-y twiddle table in frag order
// (folds the c2r alpha(ky)/256 scaling): wif[ntg*512 + l*8 + j] =
// pack(Wi[k=(l>>4)*8+j][y=ntg*16+(l&15)]).
// ---------------------------------------------------------------------------
__global__ void k_prep_dec(const float* __restrict__ w1, const float* __restrict__ w2,
                           const float* __restrict__ pww,
                           unsigned* __restrict__ wb1p, unsigned* __restrict__ wb2p,
                           unsigned* __restrict__ wpwp, unsigned* __restrict__ wif) {
    int tid = threadIdx.x;
    for (int idx = tid; idx < 3 * 2 * 16 * 32; idx += 256) {
        int k = idx & 31, n16 = (idx >> 5) & 15, nb = (idx >> 9) & 1, d = idx >> 10;
        wb1p[idx] = pack_hl(w1[d * 1024 + k * 32 + nb * 16 + n16]);
    }
    for (int idx = tid; idx < 3 * 8 * 16 * 32; idx += 256) {
        int k = idx & 31, n16 = (idx >> 5) & 15, blk = (idx >> 9) & 7, d = idx >> 12;
        wb2p[idx] = pack_hl(w2[d * 4096 + k * 128 + blk * 16 + n16]);
    }
    for (int idx = tid; idx < NL * 1024; idx += 256)   // [l][o][i] layout kept
        wpwp[idx] = pack_hl(pww[idx]);
    for (int idx = tid; idx < 16 * 64 * 8; idx += 256) {
        int j = idx & 7, l = (idx >> 3) & 63, ntg = idx >> 9;
        int k = ((l >> 4) << 3) + j, y = (ntg << 4) + (l & 15);
        int ky = k >> 1, p = k & 1;
        float v;
        if (k == 0)      v = 1.0f / 256.0f;
        else if (k == 1) v = 0.0f;
        else {
            float ang = TWO_PI_OVER_N * (float)((ky * y) & 255);
            v = p ? (-2.0f / 256.0f) * sinf(ang) : (2.0f / 256.0f) * cosf(ang);
        }
        wif[idx] = pack_hl(v);
    }
}

// ---------------------------------------------------------------------------
// Lifting
// ---------------------------------------------------------------------------
__global__ void k_lift(const float* __restrict__ bc, const float* __restrict__ xg,
                       const float* __restrict__ yg, const float* __restrict__ w,
                       const float* __restrict__ bias, float* __restrict__ h) {
    int idx = blockIdx.x * 256 + threadIdx.x;   // over B*N*N
    int b = idx >> 16, pos = idx & 65535;
    float i0 = bc[b * 3 + 0], i1 = bc[b * 3 + 1], i2 = bc[b * 3 + 2];
    float i3 = xg[idx], i4 = yg[idx];
#pragma unroll
    for (int c = 0; c < CW; ++c) {
        float v = i0 * w[c] + i1 * w[CW + c] + i2 * w[2 * CW + c]
                + i3 * w[3 * CW + c] + i4 * w[4 * CW + c] + bias[c];
        h[((size_t)(b * CW + c) << 16) + pos] = v;
    }
}

// ---------------------------------------------------------------------------
// Forward DFT along y (unchanged from round 8, passing)
// ---------------------------------------------------------------------------
__global__ void k_fwd_y(const float* __restrict__ h, const float* __restrict__ Wf,
                        float* __restrict__ gy) {
    __shared__ float smem[16384];      // tile[64][256] (swizzled)  ∪  red[4][64][33]
    int tid = threadIdx.x;
    int wv = tid >> 6, lane = tid & 63;
    int row0 = blockIdx.x * 64;
    const float* hp = h + (size_t)row0 * 256;
#pragma unroll 8
    for (int k = 0; k < 64; ++k)       // row k, y = tid  (coalesced)
        smem[k * 256 + (tid ^ (k & 31))] = hp[k * 256 + tid];
    __syncthreads();

    const float* wp = Wf + wv * 64 * 32;
    const float* trow = &smem[lane * 256];
    int swz = lane & 31;
    float acc[32];
#pragma unroll
    for (int c = 0; c < 32; ++c) acc[c] = 0.f;
#pragma unroll 4
    for (int yy = 0; yy < 64; ++yy) {
        float hv = trow[(wv * 64 + yy) ^ swz];
        const float* wr0 = wp + yy * 32;        // wave-uniform -> s_load
#pragma unroll
        for (int c = 0; c < 32; ++c) acc[c] += hv * wr0[c];
    }
    __syncthreads();                    // tile dead; reuse LDS as red
    float (*red)[64][33] = (float(*)[64][33])smem;
#pragma unroll
    for (int c = 0; c < 32; ++c) red[wv][lane][c] = acc[c];
    __syncthreads();
#pragma unroll
    for (int k = 0; k < 8; ++k) {
        int o = k * 256 + tid;          // 0..2047
        int r = o >> 5, c = o & 31;
        float v = red[0][r][c] + red[1][r][c] + red[2][r][c] + red[3][r][c];
        gy[(size_t)(row0 + r) * 32 + c] = v;
    }
}

// ---------------------------------------------------------------------------
// Forward DFT along x, 1024 threads (split-K + LDS reduce) — unchanged
// ---------------------------------------------------------------------------
__global__ void __launch_bounds__(1024) k_fwd_x(const float* __restrict__ gy,
                                                float* __restrict__ Xf) {
    __shared__ float g[8192];           // (x, c) 32 KB
    __shared__ float part[4][256][2];   // 8 KB
    __shared__ float ct[256], st[256];
    int tid = threadIdx.x;
    if (tid < 256) {
        float ang = (float)tid * TWO_PI_OVER_N;
        ct[tid] = cosf(ang);
        st[tid] = sinf(ang);
    }
    size_t base = (size_t)blockIdx.x * 8192;
#pragma unroll
    for (int j = 0; j < 8; ++j) g[j * 1024 + tid] = gy[base + j * 1024 + tid];
    __syncthreads();

    int t = tid & 255, xq = tid >> 8;
    int kx = t >> 4, ky = t & 15;
    float ar = 0.f, ai = 0.f;
    int x0 = xq * 64;
    int idx = (kx * x0) & 255;
#pragma unroll 4
    for (int x = x0; x < x0 + 64; ++x) {
        float c = ct[idx], s = st[idx];
        float gr = g[x * 32 + ky * 2], gi = g[x * 32 + ky * 2 + 1];
        ar += gr * c + gi * s;          // e^{-i}
        ai += gi * c - gr * s;
        idx = (idx + kx) & 255;
    }
    part[xq][t][0] = ar;
    part[xq][t][1] = ai;
    __syncthreads();
    if (tid < 256) {
        float a0 = part[0][tid][0] + part[1][tid][0] + part[2][tid][0] + part[3][tid][0];
        float a1 = part[0][tid][1] + part[1][tid][1] + part[2][tid][1] + part[3][tid][1];
        Xf[((size_t)blockIdx.x * 256 + tid) * 2 + 0] = a0 * (1.0f / 256.0f);
        Xf[((size_t)blockIdx.x * 256 + tid) * 2 + 1] = a1 * (1.0f / 256.0f);
    }
}

// ---------------------------------------------------------------------------
// Fused mode-mix + inverse x-DFT, 1024 threads. Block = (b,o) — unchanged
// ---------------------------------------------------------------------------
__global__ void __launch_bounds__(1024) k_spec(const float* __restrict__ Xf,
                                               const float* __restrict__ wr,
                                               const float* __restrict__ wi,
                                               float* __restrict__ gi) {
    __shared__ float tl[512];
    __shared__ float pp[4][256][2];
    __shared__ float ct[256], st[256];
    int tid = threadIdx.x;
    if (tid < 256) {
        float ang = (float)tid * TWO_PI_OVER_N;
        ct[tid] = cosf(ang);
        st[tid] = sinf(ang);
    }
    int b = blockIdx.x >> 5, o = blockIdx.x & 31;
    int t = tid & 255, ig = tid >> 8;

    // phase 1: mix (split-K over i)
    float tr = 0.f, ti = 0.f;
    const float2* xp = (const float2*)Xf + (size_t)b * 8192 + t;
    const float* wrp = wr + (size_t)o * 256 + t;
    const float* wip = wi + (size_t)o * 256 + t;
#pragma unroll
    for (int i = ig * 8; i < ig * 8 + 8; ++i) {
        float2 xv = xp[i * 256];
        float wrv = wrp[(size_t)i * 8192];
        float wiv = wip[(size_t)i * 8192];
        tr += xv.x * wrv - xv.y * wiv;
        ti += xv.x * wiv + xv.y * wrv;
    }
    pp[ig][t][0] = tr;
    pp[ig][t][1] = ti;
    __syncthreads();
    if (tid < 256) {
        tl[tid * 2 + 0] = pp[0][tid][0] + pp[1][tid][0] + pp[2][tid][0] + pp[3][tid][0];
        tl[tid * 2 + 1] = pp[0][tid][1] + pp[1][tid][1] + pp[2][tid][1] + pp[3][tid][1];
    }
    __syncthreads();

    // phase 2: inverse x-DFT; thread handles 4 ky for one x
    int x = t, kg = ig;
    float gre[4], gim[4];
#pragma unroll
    for (int k = 0; k < 4; ++k) { gre[k] = 0.f; gim[k] = 0.f; }
#pragma unroll 4
    for (int kx = 0; kx < 16; ++kx) {
        int idx = (kx * x) & 255;
        float c = ct[idx], s = st[idx];
#pragma unroll
        for (int k = 0; k < 4; ++k) {
            int ky = kg * 4 + k;
            float t2r = tl[(kx * 16 + ky) * 2 + 0];
            float t2i = tl[(kx * 16 + ky) * 2 + 1];
            gre[k] += t2r * c - t2i * s;   // e^{+i}
            gim[k] += t2i * c + t2r * s;
        }
    }
    size_t ob = (((size_t)b * 256 + x) * 32 + o) * 32;
#pragma unroll
    for (int k = 0; k < 4; ++k) {
        gi[ob + (kg * 4 + k) * 2 + 0] = gre[k];
        gi[ob + (kg * 4 + k) * 2 + 1] = gim[k];
    }
}

// ---------------------------------------------------------------------------
// MFMA k_update: per block (b,x): out[o][y] = h_old[o][y] +
//   gelu( gt(32x32) @ Wi(32x256) + pw_w(32x32) @ h(32x256) + pwb[o] )
// Two K=32 GEMMs accumulated into one acc; bf16 hi/lo split x3 each.
// 4 waves x 64 y each; no LDS, no barriers; all loads precede all stores.
// Frag conventions (proven in decode): A[l&15][(l>>4)*8+j];
// B[(l>>4)*8+j][l&15]; D[(l>>4)*4+r][l&15].
// ---------------------------------------------------------------------------
__global__ void __launch_bounds__(256) k_update(float* __restrict__ h,
        const float* __restrict__ gi, const unsigned* __restrict__ wpwp,
        const float* __restrict__ pwb, const unsigned* __restrict__ wif) {
    int tid = threadIdx.x;
    int wv = tid >> 6, l = tid & 63;
    int l15 = l & 15, lk = l >> 4;
    int bx = blockIdx.x, b = bx >> 8, x = bx & 255;
    float* hx = h + (((size_t)b * 32) << 16) + x * 256;   // + c*65536 + y

    // ---- A-frags: gt (runtime, from gi) and W (prepacked) ----
    bf16x8 gth[2], gtl[2], wh[2], wl[2];
    const float* gp = gi + (size_t)bx * 1024;
#pragma unroll
    for (int mt = 0; mt < 2; ++mt) {
        const float* ap = gp + (mt * 16 + l15) * 32 + lk * 8;
        float4 a0 = *(const float4*)ap;
        float4 a1 = *(const float4*)(ap + 4);
        float av[8] = {a0.x, a0.y, a0.z, a0.w, a1.x, a1.y, a1.z, a1.w};
#pragma unroll
        for (int j = 0; j < 8; ++j) {
            unsigned pb = pack_hl(av[j]);
            gth[mt][j] = (short)(pb >> 16);
            gtl[mt][j] = (short)(pb & 0xffffu);
        }
        const unsigned* wp = wpwp + (mt * 16 + l15) * 32 + lk * 8;
        u32x4 w0 = *(const u32x4*)wp;
        u32x4 w1 = *(const u32x4*)(wp + 4);
#pragma unroll
        for (int j = 0; j < 4; ++j) {
            wh[mt][j]     = (short)(w0[j] >> 16);
            wl[mt][j]     = (short)(w0[j] & 0xffffu);
            wh[mt][4 + j] = (short)(w1[j] >> 16);
            wl[mt][4 + j] = (short)(w1[j] & 0xffffu);
        }
    }

    // ---- MFMA phase: acc[mt][nt], all loads, no stores ----
    f32x4 acc[2][4];
#pragma unroll
    for (int nt = 0; nt < 4; ++nt) {
        int y = wv * 64 + nt * 16 + l15;
        int ntg = wv * 4 + nt;
        const unsigned* qp = wif + ntg * 512 + l * 8;
        u32x4 q0 = *(const u32x4*)qp;
        u32x4 q1 = *(const u32x4*)(qp + 4);
        bf16x8 wih, wil;
#pragma unroll
        for (int j = 0; j < 4; ++j) {
            wih[j]     = (short)(q0[j] >> 16);
            wil[j]     = (short)(q0[j] & 0xffffu);
            wih[4 + j] = (short)(q1[j] >> 16);
            wil[4 + j] = (short)(q1[j] & 0xffffu);
        }
        bf16x8 hbh, hbl;
#pragma unroll
        for (int j = 0; j < 8; ++j) {
            float v = hx[((size_t)(lk * 8 + j) << 16) + y];
            unsigned pb = pack_hl(v);
            hbh[j] = (short)(pb >> 16);
            hbl[j] = (short)(pb & 0xffffu);
        }
#pragma unroll
        for (int mt = 0; mt < 2; ++mt) {
            f32x4 a = {0.f, 0.f, 0.f, 0.f};
            a = __builtin_amdgcn_mfma_f32_16x16x32_bf16(gtl[mt], wih, a, 0, 0, 0);
            a = __builtin_amdgcn_mfma_f32_16x16x32_bf16(gth[mt], wil, a, 0, 0, 0);
            a = __builtin_amdgcn_mfma_f32_16x16x32_bf16(gth[mt], wih, a, 0, 0, 0);
            a = __builtin_amdgcn_mfma_f32_16x16x32_bf16(wl[mt],  hbh, a, 0, 0, 0);
            a = __builtin_amdgcn_mfma_f32_16x16x32_bf16(wh[mt],  hbl, a, 0, 0, 0);
            a = __builtin_amdgcn_mfma_f32_16x16x32_bf16(wh[mt],  hbh, a, 0, 0, 0);
            acc[mt][nt] = a;
        }
    }

    // ---- epilogue: load all h_old, then gelu + residual + store ----
    float hold[2][4][4];
#pragma unroll
    for (int mt = 0; mt < 2; ++mt)
#pragma unroll
        for (int nt = 0; nt < 4; ++nt) {
            int y = wv * 64 + nt * 16 + l15;
#pragma unroll
            for (int r = 0; r < 4; ++r)
                hold[mt][nt][r] = hx[((size_t)(mt * 16 + lk * 4 + r) << 16) + y];
        }
#pragma unroll
    for (int mt = 0; mt < 2; ++mt)
#pragma unroll
        for (int nt = 0; nt < 4; ++nt) {
            int y = wv * 64 + nt * 16 + l15;
#pragma unroll
            for (int r = 0; r < 4; ++r) {
                int o = mt * 16 + lk * 4 + r;
                float u = acc[mt][nt][r] + pwb[o];
                hx[((size_t)o << 16) + y] = hold[mt][nt][r] + gelu_f(u);
            }
        }
}

// ---------------------------------------------------------------------------
// MFMA decoder (unchanged from round 8, passing)
// ---------------------------------------------------------------------------
__global__ void __launch_bounds__(256) k_decode(const float* __restrict__ h,
        const unsigned* __restrict__ wb1p, const float* __restrict__ b1,
        const unsigned* __restrict__ wb2p, const float* __restrict__ b2,
        const float* __restrict__ w3, const float* __restrict__ b3,
        float* __restrict__ out) {
    __shared__ unsigned z1s[4][64][32];     // per-wave, XOR-swizzled 16B slots
    int tid = threadIdx.x;
    int wv = tid >> 6, l = tid & 63;
    int l15 = l & 15, lk = l >> 4;
    int b = blockIdx.x >> 8;
    int pos0 = (blockIdx.x & 255) * 256;

    bf16x8 ah[4], al[4];
    const float* hb = h + (((size_t)b * 32) << 16) + pos0;
#pragma unroll
    for (int mt = 0; mt < 4; ++mt) {
        int p = wv * 64 + mt * 16 + l15;
#pragma unroll
        for (int j = 0; j < 8; ++j) {
            float v = hb[((size_t)(lk * 8 + j) << 16) + p];
            unsigned pb = pack_hl(v);
            ah[mt][j] = (short)(pb >> 16);
            al[mt][j] = (short)(pb & 0xffffu);
        }
    }

    size_t gbase = (size_t)blockIdx.x * 256 + wv * 64;
    for (int d = 0; d < 3; ++d) {
        bf16x8 w1h[2], w1l[2];
        float bias1[2];
#pragma unroll
        for (int nb = 0; nb < 2; ++nb) {
            const unsigned* wp = wb1p + (((d * 2 + nb) * 16 + l15) * 32 + lk * 8);
            u32x4 w0 = *(const u32x4*)wp;
            u32x4 w1v = *(const u32x4*)(wp + 4);
#pragma unroll
            for (int j = 0; j < 4; ++j) {
                w1h[nb][j]     = (short)(w0[j] >> 16);
                w1l[nb][j]     = (short)(w0[j] & 0xffffu);
                w1h[nb][4 + j] = (short)(w1v[j] >> 16);
                w1l[nb][4 + j] = (short)(w1v[j] & 0xffffu);
            }
            bias1[nb] = b1[d * 32 + nb * 16 + l15];
        }
#pragma unroll
        for (int mt = 0; mt < 4; ++mt) {
#pragma unroll
            for (int nb = 0; nb < 2; ++nb) {
                f32x4 acc = {0.f, 0.f, 0.f, 0.f};
                acc = __builtin_amdgcn_mfma_f32_16x16x32_bf16(al[mt], w1h[nb], acc, 0, 0, 0);
                acc = __builtin_amdgcn_mfma_f32_16x16x32_bf16(ah[mt], w1l[nb], acc, 0, 0, 0);
                acc = __builtin_amdgcn_mfma_f32_16x16x32_bf16(ah[mt], w1h[nb], acc, 0, 0, 0);
                int c = nb * 16 + l15;
#pragma unroll
                for (int r = 0; r < 4; ++r) {
                    float z = gelu_f(acc[r] + bias1[nb]);
                    int rw = mt * 16 + lk * 4 + r;
                    z1s[wv][rw][(((c >> 2) ^ (rw & 7)) << 2) | (c & 3)] = pack_hl(z);
                }
            }
        }
        bf16x8 zah[4], zal[4];
#pragma unroll
        for (int mt = 0; mt < 4; ++mt) {
            int rwr = mt * 16 + l15;
            int sl0 = (2 * lk) ^ (rwr & 7);
            int sl1 = (2 * lk + 1) ^ (rwr & 7);
            u32x4 q0 = *(const u32x4*)&z1s[wv][rwr][sl0 << 2];
            u32x4 q1 = *(const u32x4*)&z1s[wv][rwr][sl1 << 2];
#pragma unroll
            for (int j = 0; j < 4; ++j) {
                zah[mt][j]     = (short)(q0[j] >> 16);
                zal[mt][j]     = (short)(q0[j] & 0xffffu);
                zah[mt][4 + j] = (short)(q1[j] >> 16);
                zal[mt][4 + j] = (short)(q1[j] & 0xffffu);
            }
        }
        float p3[4][4];
#pragma unroll
        for (int mt = 0; mt < 4; ++mt)
#pragma unroll
            for (int r = 0; r < 4; ++r) p3[mt][r] = 0.f;
#pragma unroll 2
        for (int blk = 0; blk < 8; ++blk) {
            const unsigned* wp = wb2p + (((d * 8 + blk) * 16 + l15) * 32 + lk * 8);
            u32x4 w0 = *(const u32x4*)wp;
            u32x4 w1v = *(const u32x4*)(wp + 4);
            bf16x8 bh, bl2;
#pragma unroll
            for (int j = 0; j < 4; ++j) {
                bh[j]      = (short)(w0[j] >> 16);
                bl2[j]     = (short)(w0[j] & 0xffffu);
                bh[4 + j]  = (short)(w1v[j] >> 16);
                bl2[4 + j] = (short)(w1v[j] & 0xffffu);
            }
            float bias2 = b2[d * 128 + blk * 16 + l15];
            float w3v   = w3[d * 128 + blk * 16 + l15];
#pragma unroll
            for (int mt = 0; mt < 4; ++mt) {
                f32x4 acc = {0.f, 0.f, 0.f, 0.f};
                acc = __builtin_amdgcn_mfma_f32_16x16x32_bf16(zal[mt], bh, acc, 0, 0, 0);
                acc = __builtin_amdgcn_mfma_f32_16x16x32_bf16(zah[mt], bl2, acc, 0, 0, 0);
                acc = __builtin_amdgcn_mfma_f32_16x16x32_bf16(zah[mt], bh, acc, 0, 0, 0);
#pragma unroll
                for (int r = 0; r < 4; ++r)
                    p3[mt][r] = fmaf(gelu_f(acc[r] + bias2), w3v, p3[mt][r]);
            }
        }
        float b3d = b3[d];
#pragma unroll
        for (int mt = 0; mt < 4; ++mt) {
#pragma unroll
            for (int r = 0; r < 4; ++r) {
                float v = p3[mt][r];
                v += __shfl_xor(v, 1, 64);
                v += __shfl_xor(v, 2, 64);
                v += __shfl_xor(v, 4, 64);
                v += __shfl_xor(v, 8, 64);
                if (l15 == r)
                    out[(gbase + mt * 16 + lk * 4 + r) * 3 + d] = v + b3d;
            }
        }
    }
}

// ---------------------------------------------------------------------------
// Workspace (floats): gy and gi share one region (disjoint lifetimes).
// Total = 19,041,280 floats = 76.2 MB (76.6 proven safe rounds 3-8).
// ---------------------------------------------------------------------------
extern "C" void kernel_launch(void* const* d_in, const int* in_sizes, int n_in,
                              void* d_out, int out_size, void* d_ws, size_t ws_size,
                              hipStream_t stream) {
    const float* bc      = (const float*)d_in[0];
    const float* xg      = (const float*)d_in[1];
    const float* yg      = (const float*)d_in[2];
    const float* mlp1_w  = (const float*)d_in[3];
    const float* mlp1_b  = (const float*)d_in[4];
    const float* spec_wr = (const float*)d_in[5];
    const float* spec_wi = (const float*)d_in[6];
    const float* pw_w    = (const float*)d_in[7];
    const float* pw_b    = (const float*)d_in[8];
    const float* dec_w1  = (const float*)d_in[9];
    const float* dec_b1  = (const float*)d_in[10];
    const float* dec_w2  = (const float*)d_in[11];
    const float* dec_b2  = (const float*)d_in[12];
    const float* dec_w3  = (const float*)d_in[13];
    const float* dec_b3  = (const float*)d_in[14];
    float* out = (float*)d_out;

    float* h    = (float*)d_ws;               // 16,777,216 floats
    float* spec = h + 16777216;               //  2,097,152 (shared gy / gi)
    float* Xf   = spec + 2097152;             //    131,072
    float* Wf   = Xf + 131072;                //      8,192
    unsigned* wb1p = (unsigned*)(Wf + 8192);  //      3,072
    unsigned* wb2p = wb1p + 3072;             //     12,288
    unsigned* wpwp = wb2p + 12288;            //      4,096
    unsigned* wif  = wpwp + 4096;             //      8,192
    float* gy   = spec;
    float* gi   = spec;
    (void)ws_size; (void)n_in; (void)in_sizes; (void)out_size;

    k_twiddle<<<32, 256, 0, stream>>>(Wf);
    k_prep_dec<<<1, 256, 0, stream>>>(dec_w1, dec_w2, pw_w, wb1p, wb2p, wpwp, wif);
    k_lift<<<2048, 256, 0, stream>>>(bc, xg, yg, mlp1_w, mlp1_b, h);
    for (int l = 0; l < NL; ++l) {
        k_fwd_y<<<1024, 256, 0, stream>>>(h, Wf, gy);
        k_fwd_x<<<256, 1024, 0, stream>>>(gy, Xf);
        k_spec<<<256, 1024, 0, stream>>>(Xf, spec_wr + (size_t)l * 262144,
                                         spec_wi + (size_t)l * 262144, gi);
        k_update<<<2048, 256, 0, stream>>>(h, gi, wpwp + l * 1024,
                                           pw_b + l * 32, wif);
    }
    k_decode<<<2048, 256, 0, stream>>>(h, wb1p, dec_b1, wb2p, dec_b2,
                                       dec_w3, dec_b3, out);
}

// Round 10
// 686.866 us; speedup vs baseline: 1.4410x; 1.0571x over previous
//
#include <hip/hip_runtime.h>
#include <math.h>

// Problem constants
#define BSZ 8
#define CW  32      // WIDTH (channels)
#define NN  256     // NX = NY
#define MM  16      // modes M1 = M2
#define NL  4
#define HID 128

typedef __attribute__((ext_vector_type(8))) short bf16x8;
typedef __attribute__((ext_vector_type(4))) float f32x4;
typedef __attribute__((ext_vector_type(4))) unsigned int u32x4;

// ---------------------------------------------------------------------------
// Fast GELU via A&S 7.1.27: erf(x) ~= 1 - (1+a1x+a2x^2+a3x^3+a4x^4)^-4,
// |err| <= 5e-4 (verified at x=0.1/0.5/1/2/3). ONE transcendental (rcp),
// no exp, no clamp: P -> inf gives gelu -> relu naturally.
// gelu(v) = relu(v) - 0.5|v| * r^4.
// ---------------------------------------------------------------------------
static __device__ __forceinline__ float gelu_f(float v) {
    float av = fabsf(v);
    float u  = av * 0.70710678118654752f;
    float P  = fmaf(fmaf(fmaf(fmaf(0.078108f, u, 0.000972f), u, 0.230389f),
                         u, 0.278393f), u, 1.0f);
    float r  = __builtin_amdgcn_rcpf(P);
    float r2 = r * r;
    float r4 = r2 * r2;
    return fmaf(-0.5f * av, r4, fmaxf(v, 0.0f));
}

// fp32 -> (bf16 hi | bf16 lo) packed u32, truncation split
static __device__ __forceinline__ unsigned pack_hl(float v) {
    unsigned b  = __float_as_uint(v);
    unsigned hi = b >> 16;
    float hif   = __uint_as_float(hi << 16);
    float lo    = v - hif;
    unsigned lou = __float_as_uint(lo) >> 16;
    return (hi << 16) | lou;
}

#define TWO_PI_OVER_N (6.28318530717958647692f / 256.0f)

// ---------------------------------------------------------------------------
// Build forward-DFT twiddle matrix Wf[y][2*ky+p]: p=0 -> cos, p=1 -> -sin
// ---------------------------------------------------------------------------
__global__ void k_twiddle(float* __restrict__ Wf) {
    int idx = blockIdx.x * 256 + threadIdx.x;   // 8192 = 256 y * 32 c
    int y = idx >> 5, c = idx & 31;
    int ky = c >> 1, p = c & 1;
    int m = (ky * y) & 255;
    float ang = (float)m * TWO_PI_OVER_N;
    Wf[idx] = p ? -sinf(ang) : cosf(ang);
}

// ---------------------------------------------------------------------------
// Prep: all MFMA weight operands stored as SEPARATE hi/lo bf16-short planes
// in frag element order -> load sites get ready bf16x8 with ZERO unpack VALU.
// wb1[((d*2+nb)*16+n)*32+k]  <- dec_w1[d][k][nb*16+n]
// wb2[((d*8+blk)*16+n)*32+k] <- dec_w2[d][k][blk*16+n]
// wpw[l*1024 + o*32 + i]     <- pw_w[l][o][i]            (A-frag order)
// wif[ntg*512 + l*8 + j]     <- Wi[k=(l>>4)*8+j][y=ntg*16+(l&15)] (c2r scaled)
// ---------------------------------------------------------------------------
__global__ void k_prep_dec(const float* __restrict__ w1, const float* __restrict__ w2,
                           const float* __restrict__ pww,
                           short* __restrict__ wb1h, short* __restrict__ wb1l,
                           short* __restrict__ wb2h, short* __restrict__ wb2l,
                           short* __restrict__ wpwh, short* __restrict__ wpwl,
                           short* __restrict__ wifh, short* __restrict__ wifl) {
    int tid = threadIdx.x;
    for (int idx = tid; idx < 3 * 2 * 16 * 32; idx += 256) {
        int k = idx & 31, n16 = (idx >> 5) & 15, nb = (idx >> 9) & 1, d = idx >> 10;
        unsigned p = pack_hl(w1[d * 1024 + k * 32 + nb * 16 + n16]);
        wb1h[idx] = (short)(p >> 16);
        wb1l[idx] = (short)(p & 0xffffu);
    }
    for (int idx = tid; idx < 3 * 8 * 16 * 32; idx += 256) {
        int k = idx & 31, n16 = (idx >> 5) & 15, blk = (idx >> 9) & 7, d = idx >> 12;
        unsigned p = pack_hl(w2[d * 4096 + k * 128 + blk * 16 + n16]);
        wb2h[idx] = (short)(p >> 16);
        wb2l[idx] = (short)(p & 0xffffu);
    }
    for (int idx = tid; idx < NL * 1024; idx += 256) {
        unsigned p = pack_hl(pww[idx]);
        wpwh[idx] = (short)(p >> 16);
        wpwl[idx] = (short)(p & 0xffffu);
    }
    for (int idx = tid; idx < 16 * 64 * 8; idx += 256) {
        int j = idx & 7, l = (idx >> 3) & 63, ntg = idx >> 9;
        int k = ((l >> 4) << 3) + j, y = (ntg << 4) + (l & 15);
        int ky = k >> 1, p = k & 1;
        float v;
        if (k == 0)      v = 1.0f / 256.0f;
        else if (k == 1) v = 0.0f;
        else {
            float ang = TWO_PI_OVER_N * (float)((ky * y) & 255);
            v = p ? (-2.0f / 256.0f) * sinf(ang) : (2.0f / 256.0f) * cosf(ang);
        }
        unsigned pb = pack_hl(v);
        wifh[idx] = (short)(pb >> 16);
        wifl[idx] = (short)(pb & 0xffffu);
    }
}

// ---------------------------------------------------------------------------
// Lifting
// ---------------------------------------------------------------------------
__global__ void k_lift(const float* __restrict__ bc, const float* __restrict__ xg,
                       const float* __restrict__ yg, const float* __restrict__ w,
                       const float* __restrict__ bias, float* __restrict__ h) {
    int idx = blockIdx.x * 256 + threadIdx.x;   // over B*N*N
    int b = idx >> 16, pos = idx & 65535;
    float i0 = bc[b * 3 + 0], i1 = bc[b * 3 + 1], i2 = bc[b * 3 + 2];
    float i3 = xg[idx], i4 = yg[idx];
#pragma unroll
    for (int c = 0; c < CW; ++c) {
        float v = i0 * w[c] + i1 * w[CW + c] + i2 * w[2 * CW + c]
                + i3 * w[3 * CW + c] + i4 * w[4 * CW + c] + bias[c];
        h[((size_t)(b * CW + c) << 16) + pos] = v;
    }
}

// ---------------------------------------------------------------------------
// Forward DFT along y (unchanged, passing)
// ---------------------------------------------------------------------------
__global__ void k_fwd_y(const float* __restrict__ h, const float* __restrict__ Wf,
                        float* __restrict__ gy) {
    __shared__ float smem[16384];      // tile[64][256] (swizzled)  ∪  red[4][64][33]
    int tid = threadIdx.x;
    int wv = tid >> 6, lane = tid & 63;
    int row0 = blockIdx.x * 64;
    const float* hp = h + (size_t)row0 * 256;
#pragma unroll 8
    for (int k = 0; k < 64; ++k)       // row k, y = tid  (coalesced)
        smem[k * 256 + (tid ^ (k & 31))] = hp[k * 256 + tid];
    __syncthreads();

    const float* wp = Wf + wv * 64 * 32;
    const float* trow = &smem[lane * 256];
    int swz = lane & 31;
    float acc[32];
#pragma unroll
    for (int c = 0; c < 32; ++c) acc[c] = 0.f;
#pragma unroll 4
    for (int yy = 0; yy < 64; ++yy) {
        float hv = trow[(wv * 64 + yy) ^ swz];
        const float* wr0 = wp + yy * 32;        // wave-uniform -> s_load
#pragma unroll
        for (int c = 0; c < 32; ++c) acc[c] += hv * wr0[c];
    }
    __syncthreads();                    // tile dead; reuse LDS as red
    float (*red)[64][33] = (float(*)[64][33])smem;
#pragma unroll
    for (int c = 0; c < 32; ++c) red[wv][lane][c] = acc[c];
    __syncthreads();
#pragma unroll
    for (int k = 0; k < 8; ++k) {
        int o = k * 256 + tid;          // 0..2047
        int r = o >> 5, c = o & 31;
        float v = red[0][r][c] + red[1][r][c] + red[2][r][c] + red[3][r][c];
        gy[(size_t)(row0 + r) * 32 + c] = v;
    }
}

// ---------------------------------------------------------------------------
// Forward DFT along x, 1024 threads (split-K + LDS reduce) — unchanged
// ---------------------------------------------------------------------------
__global__ void __launch_bounds__(1024) k_fwd_x(const float* __restrict__ gy,
                                                float* __restrict__ Xf) {
    __shared__ float g[8192];           // (x, c) 32 KB
    __shared__ float part[4][256][2];   // 8 KB
    __shared__ float ct[256], st[256];
    int tid = threadIdx.x;
    if (tid < 256) {
        float ang = (float)tid * TWO_PI_OVER_N;
        ct[tid] = cosf(ang);
        st[tid] = sinf(ang);
    }
    size_t base = (size_t)blockIdx.x * 8192;
#pragma unroll
    for (int j = 0; j < 8; ++j) g[j * 1024 + tid] = gy[base + j * 1024 + tid];
    __syncthreads();

    int t = tid & 255, xq = tid >> 8;
    int kx = t >> 4, ky = t & 15;
    float ar = 0.f, ai = 0.f;
    int x0 = xq * 64;
    int idx = (kx * x0) & 255;
#pragma unroll 4
    for (int x = x0; x < x0 + 64; ++x) {
        float c = ct[idx], s = st[idx];
        float gr = g[x * 32 + ky * 2], gi = g[x * 32 + ky * 2 + 1];
        ar += gr * c + gi * s;          // e^{-i}
        ai += gi * c - gr * s;
        idx = (idx + kx) & 255;
    }
    part[xq][t][0] = ar;
    part[xq][t][1] = ai;
    __syncthreads();
    if (tid < 256) {
        float a0 = part[0][tid][0] + part[1][tid][0] + part[2][tid][0] + part[3][tid][0];
        float a1 = part[0][tid][1] + part[1][tid][1] + part[2][tid][1] + part[3][tid][1];
        Xf[((size_t)blockIdx.x * 256 + tid) * 2 + 0] = a0 * (1.0f / 256.0f);
        Xf[((size_t)blockIdx.x * 256 + tid) * 2 + 1] = a1 * (1.0f / 256.0f);
    }
}

// ---------------------------------------------------------------------------
// Fused mode-mix + inverse x-DFT, 1024 threads. Block = (b,o) — unchanged
// ---------------------------------------------------------------------------
__global__ void __launch_bounds__(1024) k_spec(const float* __restrict__ Xf,
                                               const float* __restrict__ wr,
                                               const float* __restrict__ wi,
                                               float* __restrict__ gi) {
    __shared__ float tl[512];
    __shared__ float pp[4][256][2];
    __shared__ float ct[256], st[256];
    int tid = threadIdx.x;
    if (tid < 256) {
        float ang = (float)tid * TWO_PI_OVER_N;
        ct[tid] = cosf(ang);
        st[tid] = sinf(ang);
    }
    int b = blockIdx.x >> 5, o = blockIdx.x & 31;
    int t = tid & 255, ig = tid >> 8;

    // phase 1: mix (split-K over i)
    float tr = 0.f, ti = 0.f;
    const float2* xp = (const float2*)Xf + (size_t)b * 8192 + t;
    const float* wrp = wr + (size_t)o * 256 + t;
    const float* wip = wi + (size_t)o * 256 + t;
#pragma unroll
    for (int i = ig * 8; i < ig * 8 + 8; ++i) {
        float2 xv = xp[i * 256];
        float wrv = wrp[(size_t)i * 8192];
        float wiv = wip[(size_t)i * 8192];
        tr += xv.x * wrv - xv.y * wiv;
        ti += xv.x * wiv + xv.y * wrv;
    }
    pp[ig][t][0] = tr;
    pp[ig][t][1] = ti;
    __syncthreads();
    if (tid < 256) {
        tl[tid * 2 + 0] = pp[0][tid][0] + pp[1][tid][0] + pp[2][tid][0] + pp[3][tid][0];
        tl[tid * 2 + 1] = pp[0][tid][1] + pp[1][tid][1] + pp[2][tid][1] + pp[3][tid][1];
    }
    __syncthreads();

    // phase 2: inverse x-DFT; thread handles 4 ky for one x
    int x = t, kg = ig;
    float gre[4], gim[4];
#pragma unroll
    for (int k = 0; k < 4; ++k) { gre[k] = 0.f; gim[k] = 0.f; }
#pragma unroll 4
    for (int kx = 0; kx < 16; ++kx) {
        int idx = (kx * x) & 255;
        float c = ct[idx], s = st[idx];
#pragma unroll
        for (int k = 0; k < 4; ++k) {
            int ky = kg * 4 + k;
            float t2r = tl[(kx * 16 + ky) * 2 + 0];
            float t2i = tl[(kx * 16 + ky) * 2 + 1];
            gre[k] += t2r * c - t2i * s;   // e^{+i}
            gim[k] += t2i * c + t2r * s;
        }
    }
    size_t ob = (((size_t)b * 256 + x) * 32 + o) * 32;
#pragma unroll
    for (int k = 0; k < 4; ++k) {
        gi[ob + (kg * 4 + k) * 2 + 0] = gre[k];
        gi[ob + (kg * 4 + k) * 2 + 1] = gim[k];
    }
}

// ---------------------------------------------------------------------------
// MFMA k_update with split-plane weights (zero unpack for W and Wi frags)
// ---------------------------------------------------------------------------
__global__ void __launch_bounds__(256) k_update(float* __restrict__ h,
        const float* __restrict__ gi,
        const short* __restrict__ wpwh, const short* __restrict__ wpwl,
        const float* __restrict__ pwb,
        const short* __restrict__ wifh, const short* __restrict__ wifl) {
    int tid = threadIdx.x;
    int wv = tid >> 6, l = tid & 63;
    int l15 = l & 15, lk = l >> 4;
    int bx = blockIdx.x, b = bx >> 8, x = bx & 255;
    float* hx = h + (((size_t)b * 32) << 16) + x * 256;   // + c*65536 + y

    // ---- A-frags: gt (runtime, from gi) and W (prepacked planes) ----
    bf16x8 gth[2], gtl[2], wh[2], wl[2];
    const float* gp = gi + (size_t)bx * 1024;
#pragma unroll
    for (int mt = 0; mt < 2; ++mt) {
        const float* ap = gp + (mt * 16 + l15) * 32 + lk * 8;
        float4 a0 = *(const float4*)ap;
        float4 a1 = *(const float4*)(ap + 4);
        float av[8] = {a0.x, a0.y, a0.z, a0.w, a1.x, a1.y, a1.z, a1.w};
#pragma unroll
        for (int j = 0; j < 8; ++j) {
            unsigned pb = pack_hl(av[j]);
            gth[mt][j] = (short)(pb >> 16);
            gtl[mt][j] = (short)(pb & 0xffffu);
        }
        int wbase = (mt * 16 + l15) * 32 + lk * 8;
        wh[mt] = *(const bf16x8*)(wpwh + wbase);
        wl[mt] = *(const bf16x8*)(wpwl + wbase);
    }

    // ---- MFMA phase: acc[mt][nt], all loads, no stores ----
    f32x4 acc[2][4];
#pragma unroll
    for (int nt = 0; nt < 4; ++nt) {
        int y = wv * 64 + nt * 16 + l15;
        int ntg = wv * 4 + nt;
        int qb = ntg * 512 + l * 8;
        bf16x8 wih = *(const bf16x8*)(wifh + qb);
        bf16x8 wil = *(const bf16x8*)(wifl + qb);
        bf16x8 hbh, hbl;
#pragma unroll
        for (int j = 0; j < 8; ++j) {
            float v = hx[((size_t)(lk * 8 + j) << 16) + y];
            unsigned pb = pack_hl(v);
            hbh[j] = (short)(pb >> 16);
            hbl[j] = (short)(pb & 0xffffu);
        }
#pragma unroll
        for (int mt = 0; mt < 2; ++mt) {
            f32x4 a = {0.f, 0.f, 0.f, 0.f};
            a = __builtin_amdgcn_mfma_f32_16x16x32_bf16(gtl[mt], wih, a, 0, 0, 0);
            a = __builtin_amdgcn_mfma_f32_16x16x32_bf16(gth[mt], wil, a, 0, 0, 0);
            a = __builtin_amdgcn_mfma_f32_16x16x32_bf16(gth[mt], wih, a, 0, 0, 0);
            a = __builtin_amdgcn_mfma_f32_16x16x32_bf16(wl[mt],  hbh, a, 0, 0, 0);
            a = __builtin_amdgcn_mfma_f32_16x16x32_bf16(wh[mt],  hbl, a, 0, 0, 0);
            a = __builtin_amdgcn_mfma_f32_16x16x32_bf16(wh[mt],  hbh, a, 0, 0, 0);
            acc[mt][nt] = a;
        }
    }

    // ---- epilogue: load all h_old, then gelu + residual + store ----
    float hold[2][4][4];
#pragma unroll
    for (int mt = 0; mt < 2; ++mt)
#pragma unroll
        for (int nt = 0; nt < 4; ++nt) {
            int y = wv * 64 + nt * 16 + l15;
#pragma unroll
            for (int r = 0; r < 4; ++r)
                hold[mt][nt][r] = hx[((size_t)(mt * 16 + lk * 4 + r) << 16) + y];
        }
#pragma unroll
    for (int mt = 0; mt < 2; ++mt)
#pragma unroll
        for (int nt = 0; nt < 4; ++nt) {
            int y = wv * 64 + nt * 16 + l15;
#pragma unroll
            for (int r = 0; r < 4; ++r) {
                int o = mt * 16 + lk * 4 + r;
                float u = acc[mt][nt][r] + pwb[o];
                hx[((size_t)o << 16) + y] = hold[mt][nt][r] + gelu_f(u);
            }
        }
}

// ---------------------------------------------------------------------------
// MFMA decoder with split-plane weights (zero unpack) + 1-trans gelu
// ---------------------------------------------------------------------------
__global__ void __launch_bounds__(256) k_decode(const float* __restrict__ h,
        const short* __restrict__ wb1h, const short* __restrict__ wb1l,
        const float* __restrict__ b1,
        const short* __restrict__ wb2h, const short* __restrict__ wb2l,
        const float* __restrict__ b2,
        const float* __restrict__ w3, const float* __restrict__ b3,
        float* __restrict__ out) {
    __shared__ unsigned z1s[4][64][32];     // per-wave, XOR-swizzled 16B slots
    int tid = threadIdx.x;
    int wv = tid >> 6, l = tid & 63;
    int l15 = l & 15, lk = l >> 4;
    int b = blockIdx.x >> 8;
    int pos0 = (blockIdx.x & 255) * 256;

    bf16x8 ah[4], al[4];
    const float* hb = h + (((size_t)b * 32) << 16) + pos0;
#pragma unroll
    for (int mt = 0; mt < 4; ++mt) {
        int p = wv * 64 + mt * 16 + l15;
#pragma unroll
        for (int j = 0; j < 8; ++j) {
            float v = hb[((size_t)(lk * 8 + j) << 16) + p];
            unsigned pb = pack_hl(v);
            ah[mt][j] = (short)(pb >> 16);
            al[mt][j] = (short)(pb & 0xffffu);
        }
    }

    size_t gbase = (size_t)blockIdx.x * 256 + wv * 64;
    for (int d = 0; d < 3; ++d) {
        bf16x8 w1h[2], w1l[2];
        float bias1[2];
#pragma unroll
        for (int nb = 0; nb < 2; ++nb) {
            int base = ((d * 2 + nb) * 16 + l15) * 32 + lk * 8;
            w1h[nb] = *(const bf16x8*)(wb1h + base);
            w1l[nb] = *(const bf16x8*)(wb1l + base);
            bias1[nb] = b1[d * 32 + nb * 16 + l15];
        }
#pragma unroll
        for (int mt = 0; mt < 4; ++mt) {
#pragma unroll
            for (int nb = 0; nb < 2; ++nb) {
                f32x4 acc = {0.f, 0.f, 0.f, 0.f};
                acc = __builtin_amdgcn_mfma_f32_16x16x32_bf16(al[mt], w1h[nb], acc, 0, 0, 0);
                acc = __builtin_amdgcn_mfma_f32_16x16x32_bf16(ah[mt], w1l[nb], acc, 0, 0, 0);
                acc = __builtin_amdgcn_mfma_f32_16x16x32_bf16(ah[mt], w1h[nb], acc, 0, 0, 0);
                int c = nb * 16 + l15;
#pragma unroll
                for (int r = 0; r < 4; ++r) {
                    float z = gelu_f(acc[r] + bias1[nb]);
                    int rw = mt * 16 + lk * 4 + r;
                    z1s[wv][rw][(((c >> 2) ^ (rw & 7)) << 2) | (c & 3)] = pack_hl(z);
                }
            }
        }
        bf16x8 zah[4], zal[4];
#pragma unroll
        for (int mt = 0; mt < 4; ++mt) {
            int rwr = mt * 16 + l15;
            int sl0 = (2 * lk) ^ (rwr & 7);
            int sl1 = (2 * lk + 1) ^ (rwr & 7);
            u32x4 q0 = *(const u32x4*)&z1s[wv][rwr][sl0 << 2];
            u32x4 q1 = *(const u32x4*)&z1s[wv][rwr][sl1 << 2];
#pragma unroll
            for (int j = 0; j < 4; ++j) {
                zah[mt][j]     = (short)(q0[j] >> 16);
                zal[mt][j]     = (short)(q0[j] & 0xffffu);
                zah[mt][4 + j] = (short)(q1[j] >> 16);
                zal[mt][4 + j] = (short)(q1[j] & 0xffffu);
            }
        }
        float p3[4][4];
#pragma unroll
        for (int mt = 0; mt < 4; ++mt)
#pragma unroll
            for (int r = 0; r < 4; ++r) p3[mt][r] = 0.f;
#pragma unroll 2
        for (int blk = 0; blk < 8; ++blk) {
            int base = ((d * 8 + blk) * 16 + l15) * 32 + lk * 8;
            bf16x8 bh  = *(const bf16x8*)(wb2h + base);
            bf16x8 bl2 = *(const bf16x8*)(wb2l + base);
            float bias2 = b2[d * 128 + blk * 16 + l15];
            float w3v   = w3[d * 128 + blk * 16 + l15];
#pragma unroll
            for (int mt = 0; mt < 4; ++mt) {
                f32x4 acc = {0.f, 0.f, 0.f, 0.f};
                acc = __builtin_amdgcn_mfma_f32_16x16x32_bf16(zal[mt], bh, acc, 0, 0, 0);
                acc = __builtin_amdgcn_mfma_f32_16x16x32_bf16(zah[mt], bl2, acc, 0, 0, 0);
                acc = __builtin_amdgcn_mfma_f32_16x16x32_bf16(zah[mt], bh, acc, 0, 0, 0);
#pragma unroll
                for (int r = 0; r < 4; ++r)
                    p3[mt][r] = fmaf(gelu_f(acc[r] + bias2), w3v, p3[mt][r]);
            }
        }
        float b3d = b3[d];
#pragma unroll
        for (int mt = 0; mt < 4; ++mt) {
#pragma unroll
            for (int r = 0; r < 4; ++r) {
                float v = p3[mt][r];
                v += __shfl_xor(v, 1, 64);
                v += __shfl_xor(v, 2, 64);
                v += __shfl_xor(v, 4, 64);
                v += __shfl_xor(v, 8, 64);
                if (l15 == r)
                    out[(gbase + mt * 16 + lk * 4 + r) * 3 + d] = v + b3d;
            }
        }
    }
}

// ---------------------------------------------------------------------------
// Workspace (floats): gy and gi share one region (disjoint lifetimes).
// Weight planes: 55296 shorts = 27648 floats. Total = 19,041,280 floats
// = 76.2 MB (proven safe rounds 3-9).
// ---------------------------------------------------------------------------
extern "C" void kernel_launch(void* const* d_in, const int* in_sizes, int n_in,
                              void* d_out, int out_size, void* d_ws, size_t ws_size,
                              hipStream_t stream) {
    const float* bc      = (const float*)d_in[0];
    const float* xg      = (const float*)d_in[1];
    const float* yg      = (const float*)d_in[2];
    const float* mlp1_w  = (const float*)d_in[3];
    const float* mlp1_b  = (const float*)d_in[4];
    const float* spec_wr = (const float*)d_in[5];
    const float* spec_wi = (const float*)d_in[6];
    const float* pw_w    = (const float*)d_in[7];
    const float* pw_b    = (const float*)d_in[8];
    const float* dec_w1  = (const float*)d_in[9];
    const float* dec_b1  = (const float*)d_in[10];
    const float* dec_w2  = (const float*)d_in[11];
    const float* dec_b2  = (const float*)d_in[12];
    const float* dec_w3  = (const float*)d_in[13];
    const float* dec_b3  = (const float*)d_in[14];
    float* out = (float*)d_out;

    float* h    = (float*)d_ws;               // 16,777,216 floats
    float* spec = h + 16777216;               //  2,097,152 (shared gy / gi)
    float* Xf   = spec + 2097152;             //    131,072
    float* Wf   = Xf + 131072;                //      8,192
    short* wb1h = (short*)(Wf + 8192);        //      3,072 shorts
    short* wb1l = wb1h + 3072;                //      3,072
    short* wb2h = wb1l + 3072;                //     12,288
    short* wb2l = wb2h + 12288;               //     12,288
    short* wpwh = wb2l + 12288;               //      4,096
    short* wpwl = wpwh + 4096;                //      4,096
    short* wifh = wpwl + 4096;                //      8,192
    short* wifl = wifh + 8192;                //      8,192
    float* gy   = spec;
    float* gi   = spec;
    (void)ws_size; (void)n_in; (void)in_sizes; (void)out_size;

    k_twiddle<<<32, 256, 0, stream>>>(Wf);
    k_prep_dec<<<1, 256, 0, stream>>>(dec_w1, dec_w2, pw_w,
                                      wb1h, wb1l, wb2h, wb2l,
                                      wpwh, wpwl, wifh, wifl);
    k_lift<<<2048, 256, 0, stream>>>(bc, xg, yg, mlp1_w, mlp1_b, h);
    for (int l = 0; l < NL; ++l) {
        k_fwd_y<<<1024, 256, 0, stream>>>(h, Wf, gy);
        k_fwd_x<<<256, 1024, 0, stream>>>(gy, Xf);
        k_spec<<<256, 1024, 0, stream>>>(Xf, spec_wr + (size_t)l * 262144,
                                         spec_wi + (size_t)l * 262144, gi);
        k_update<<<2048, 256, 0, stream>>>(h, gi, wpwh + l * 1024, wpwl + l * 1024,
                                           pw_b + l * 32, wifh, wifl);
    }
    k_decode<<<2048, 256, 0, stream>>>(h, wb1h, wb1l, dec_b1, wb2h, wb2l, dec_b2,
                                       dec_w3, dec_b3, out);
}

// Round 11
// 363.754 us; speedup vs baseline: 2.7211x; 1.8883x over previous
//
#include <hip/hip_runtime.h>
#include <math.h>

// Problem constants
#define BSZ 8
#define CW  32      // WIDTH (channels)
#define NN  256     // NX = NY
#define MM  16      // modes M1 = M2
#define NL  4
#define HID 128

typedef __attribute__((ext_vector_type(8))) short bf16x8;
typedef __attribute__((ext_vector_type(4))) float f32x4;
typedef __attribute__((ext_vector_type(4))) unsigned int u32x4;

// ---------------------------------------------------------------------------
// Fast GELU via A&S 7.1.27 (1 transcendental, |erf err| <= 5e-4)
// ---------------------------------------------------------------------------
static __device__ __forceinline__ float gelu_f(float v) {
    float av = fabsf(v);
    float u  = av * 0.70710678118654752f;
    float P  = fmaf(fmaf(fmaf(fmaf(0.078108f, u, 0.000972f), u, 0.230389f),
                         u, 0.278393f), u, 1.0f);
    float r  = __builtin_amdgcn_rcpf(P);
    float r2 = r * r;
    float r4 = r2 * r2;
    return fmaf(-0.5f * av, r4, fmaxf(v, 0.0f));
}

// fp32 -> (bf16 hi | bf16 lo) packed u32, truncation split
static __device__ __forceinline__ unsigned pack_hl(float v) {
    unsigned b  = __float_as_uint(v);
    unsigned hi = b >> 16;
    float hif   = __uint_as_float(hi << 16);
    float lo    = v - hif;
    unsigned lou = __float_as_uint(lo) >> 16;
    return (hi << 16) | lou;
}

#define TWO_PI_OVER_N (6.28318530717958647692f / 256.0f)

// ---------------------------------------------------------------------------
// Prep (grid 32): ALL MFMA weight operands as separate hi/lo bf16-short
// planes in frag element order (zero-unpack loads).
//   wb1/wb2: decoder B-frags.  wpw: update A-frags.  wif: inverse-y B-frags
//   (c2r alpha/256 folded).  wfy: forward-y DFT B-frags (raw cos/-sin),
//   wfy[((kstep*2+nt)*64+l)*8+j]: y=(kstep>>1)*64+(kstep&1)*32+(l>>4)*8+j,
//   kc=nt*16+(l&15).
// ---------------------------------------------------------------------------
__global__ void k_prep(const float* __restrict__ w1, const float* __restrict__ w2,
                       const float* __restrict__ pww,
                       short* __restrict__ wb1h, short* __restrict__ wb1l,
                       short* __restrict__ wb2h, short* __restrict__ wb2l,
                       short* __restrict__ wpwh, short* __restrict__ wpwl,
                       short* __restrict__ wifh, short* __restrict__ wifl,
                       short* __restrict__ wfyh, short* __restrict__ wfyl) {
    int t0 = blockIdx.x * 256 + threadIdx.x;
    for (int idx = t0; idx < 3 * 2 * 16 * 32; idx += 8192) {
        int k = idx & 31, n16 = (idx >> 5) & 15, nb = (idx >> 9) & 1, d = idx >> 10;
        unsigned p = pack_hl(w1[d * 1024 + k * 32 + nb * 16 + n16]);
        wb1h[idx] = (short)(p >> 16);
        wb1l[idx] = (short)(p & 0xffffu);
    }
    for (int idx = t0; idx < 3 * 8 * 16 * 32; idx += 8192) {
        int k = idx & 31, n16 = (idx >> 5) & 15, blk = (idx >> 9) & 7, d = idx >> 12;
        unsigned p = pack_hl(w2[d * 4096 + k * 128 + blk * 16 + n16]);
        wb2h[idx] = (short)(p >> 16);
        wb2l[idx] = (short)(p & 0xffffu);
    }
    for (int idx = t0; idx < NL * 1024; idx += 8192) {
        unsigned p = pack_hl(pww[idx]);
        wpwh[idx] = (short)(p >> 16);
        wpwl[idx] = (short)(p & 0xffffu);
    }
    for (int idx = t0; idx < 16 * 64 * 8; idx += 8192) {
        int j = idx & 7, l = (idx >> 3) & 63, ntg = idx >> 9;
        int k = ((l >> 4) << 3) + j, y = (ntg << 4) + (l & 15);
        int ky = k >> 1, p = k & 1;
        float v;
        if (k == 0)      v = 1.0f / 256.0f;
        else if (k == 1) v = 0.0f;
        else {
            float ang = TWO_PI_OVER_N * (float)((ky * y) & 255);
            v = p ? (-2.0f / 256.0f) * sinf(ang) : (2.0f / 256.0f) * cosf(ang);
        }
        unsigned pb = pack_hl(v);
        wifh[idx] = (short)(pb >> 16);
        wifl[idx] = (short)(pb & 0xffffu);
    }
    for (int idx = t0; idx < 16 * 64 * 8; idx += 8192) {
        int j = idx & 7, l = (idx >> 3) & 63, f = idx >> 9;
        int nt = f & 1, kstep = f >> 1;
        int y  = (kstep >> 1) * 64 + (kstep & 1) * 32 + ((l >> 4) << 3) + j;
        int kc = nt * 16 + (l & 15);
        int ky = kc >> 1, p = kc & 1;
        float ang = TWO_PI_OVER_N * (float)((ky * y) & 255);
        float v = p ? -sinf(ang) : cosf(ang);
        unsigned pb = pack_hl(v);
        wfyh[idx] = (short)(pb >> 16);
        wfyl[idx] = (short)(pb & 0xffffu);
    }
}

// ---------------------------------------------------------------------------
// Shared tail: forward y-DFT GEMM via MFMA from a per-wave LDS h-tile.
// hlsh/hlsl: wave-local [32 c][64 y] short planes, y XOR-swizzled by
// ((c&7)<<3).  gy[(b*32+c)*8192 + x*32 + kc] = sum_y h[c][y]*Wf[y][kc].
// K=256 split over 4 waves (64 each, 2 K-steps); fp32 partials reduced
// through red[4][32][33] with one barrier.
// ---------------------------------------------------------------------------
static __device__ __forceinline__ void dft_y_mfma(
        const short* __restrict__ hlsh, const short* __restrict__ hlsl,
        float* __restrict__ red,
        const short* __restrict__ wfyh, const short* __restrict__ wfyl,
        float* __restrict__ gy, int b, int x, int wv, int lk, int l15, int tid) {
    f32x4 acc2[2][2];
#pragma unroll
    for (int mt = 0; mt < 2; ++mt)
#pragma unroll
        for (int nt = 0; nt < 2; ++nt) acc2[mt][nt] = (f32x4){0.f, 0.f, 0.f, 0.f};
#pragma unroll
    for (int kk = 0; kk < 2; ++kk) {
        bf16x8 ahh[2], all2[2];
#pragma unroll
        for (int mt = 0; mt < 2; ++mt) {
            int c  = mt * 16 + l15;
            int yl = (kk * 32 + lk * 8) ^ ((c & 7) << 3);
            ahh[mt]  = *(const bf16x8*)&hlsh[c * 64 + yl];
            all2[mt] = *(const bf16x8*)&hlsl[c * 64 + yl];
        }
#pragma unroll
        for (int nt = 0; nt < 2; ++nt) {
            int fb = (((wv * 2 + kk) * 2 + nt) * 64 + (tid & 63)) * 8;
            bf16x8 bh = *(const bf16x8*)&wfyh[fb];
            bf16x8 bl = *(const bf16x8*)&wfyl[fb];
#pragma unroll
            for (int mt = 0; mt < 2; ++mt) {
                f32x4 a = acc2[mt][nt];
                a = __builtin_amdgcn_mfma_f32_16x16x32_bf16(all2[mt], bh, a, 0, 0, 0);
                a = __builtin_amdgcn_mfma_f32_16x16x32_bf16(ahh[mt],  bl, a, 0, 0, 0);
                a = __builtin_amdgcn_mfma_f32_16x16x32_bf16(ahh[mt],  bh, a, 0, 0, 0);
                acc2[mt][nt] = a;
            }
        }
    }
#pragma unroll
    for (int mt = 0; mt < 2; ++mt)
#pragma unroll
        for (int nt = 0; nt < 2; ++nt)
#pragma unroll
            for (int r = 0; r < 4; ++r)
                red[(wv * 32 + mt * 16 + lk * 4 + r) * 33 + nt * 16 + l15] =
                    acc2[mt][nt][r];
    __syncthreads();
#pragma unroll
    for (int e = 0; e < 4; ++e) {
        int idx = e * 256 + tid;
        int c = idx >> 5, kc = idx & 31;
        float v = red[(c) * 33 + kc] + red[(32 + c) * 33 + kc]
                + red[(64 + c) * 33 + kc] + red[(96 + c) * 33 + kc];
        gy[((size_t)(b * 32 + c)) * 8192 + x * 32 + kc] = v;
    }
}

// ---------------------------------------------------------------------------
// Fused lifting + forward y-DFT.  Block (b,x), thread = y.
// ---------------------------------------------------------------------------
__global__ void __launch_bounds__(256) k_lift_fy(
        const float* __restrict__ bc, const float* __restrict__ xg,
        const float* __restrict__ yg, const float* __restrict__ w,
        const float* __restrict__ bias, float* __restrict__ h,
        const short* __restrict__ wfyh, const short* __restrict__ wfyl,
        float* __restrict__ gy) {
    __shared__ short hlsh[4][2048];
    __shared__ short hlsl[4][2048];
    __shared__ float red[4224];
    int tid = threadIdx.x;
    int wv = tid >> 6, lk = (tid >> 4) & 3, l15 = tid & 15;
    int bx = blockIdx.x, b = bx >> 8, x = bx & 255;
    int y = tid;
    float i0 = bc[b * 3 + 0], i1 = bc[b * 3 + 1], i2 = bc[b * 3 + 2];
    float i3 = xg[b * 65536 + x * 256 + y];
    float i4 = yg[b * 65536 + x * 256 + y];
    size_t hb = (((size_t)b * 32) << 16) + x * 256 + y;
#pragma unroll
    for (int c = 0; c < 32; ++c) {
        float v = i0 * w[c] + i1 * w[CW + c] + i2 * w[2 * CW + c]
                + i3 * w[3 * CW + c] + i4 * w[4 * CW + c] + bias[c];
        h[hb + ((size_t)c << 16)] = v;
        unsigned pb = pack_hl(v);
        int sl = (y & 63) ^ ((c & 7) << 3);
        hlsh[wv][c * 64 + sl] = (short)(pb >> 16);
        hlsl[wv][c * 64 + sl] = (short)(pb & 0xffffu);
    }
    dft_y_mfma(&hlsh[wv][0], &hlsl[wv][0], red, wfyh, wfyl, gy, b, x, wv, lk, l15, tid);
}

// ---------------------------------------------------------------------------
// Forward DFT along x, 1024 threads (split-K + LDS reduce) — unchanged
// ---------------------------------------------------------------------------
__global__ void __launch_bounds__(1024) k_fwd_x(const float* __restrict__ gy,
                                                float* __restrict__ Xf) {
    __shared__ float g[8192];           // (x, c) 32 KB
    __shared__ float part[4][256][2];   // 8 KB
    __shared__ float ct[256], st[256];
    int tid = threadIdx.x;
    if (tid < 256) {
        float ang = (float)tid * TWO_PI_OVER_N;
        ct[tid] = cosf(ang);
        st[tid] = sinf(ang);
    }
    size_t base = (size_t)blockIdx.x * 8192;
#pragma unroll
    for (int j = 0; j < 8; ++j) g[j * 1024 + tid] = gy[base + j * 1024 + tid];
    __syncthreads();

    int t = tid & 255, xq = tid >> 8;
    int kx = t >> 4, ky = t & 15;
    float ar = 0.f, ai = 0.f;
    int x0 = xq * 64;
    int idx = (kx * x0) & 255;
#pragma unroll 4
    for (int x = x0; x < x0 + 64; ++x) {
        float c = ct[idx], s = st[idx];
        float gr = g[x * 32 + ky * 2], gi = g[x * 32 + ky * 2 + 1];
        ar += gr * c + gi * s;          // e^{-i}
        ai += gi * c - gr * s;
        idx = (idx + kx) & 255;
    }
    part[xq][t][0] = ar;
    part[xq][t][1] = ai;
    __syncthreads();
    if (tid < 256) {
        float a0 = part[0][tid][0] + part[1][tid][0] + part[2][tid][0] + part[3][tid][0];
        float a1 = part[0][tid][1] + part[1][tid][1] + part[2][tid][1] + part[3][tid][1];
        Xf[((size_t)blockIdx.x * 256 + tid) * 2 + 0] = a0 * (1.0f / 256.0f);
        Xf[((size_t)blockIdx.x * 256 + tid) * 2 + 1] = a1 * (1.0f / 256.0f);
    }
}

// ---------------------------------------------------------------------------
// Fused mode-mix + inverse x-DFT, 1024 threads. Block = (b,o) — unchanged
// ---------------------------------------------------------------------------
__global__ void __launch_bounds__(1024) k_spec(const float* __restrict__ Xf,
                                               const float* __restrict__ wr,
                                               const float* __restrict__ wi,
                                               float* __restrict__ gi) {
    __shared__ float tl[512];
    __shared__ float pp[4][256][2];
    __shared__ float ct[256], st[256];
    int tid = threadIdx.x;
    if (tid < 256) {
        float ang = (float)tid * TWO_PI_OVER_N;
        ct[tid] = cosf(ang);
        st[tid] = sinf(ang);
    }
    int b = blockIdx.x >> 5, o = blockIdx.x & 31;
    int t = tid & 255, ig = tid >> 8;

    float tr = 0.f, ti = 0.f;
    const float2* xp = (const float2*)Xf + (size_t)b * 8192 + t;
    const float* wrp = wr + (size_t)o * 256 + t;
    const float* wip = wi + (size_t)o * 256 + t;
#pragma unroll
    for (int i = ig * 8; i < ig * 8 + 8; ++i) {
        float2 xv = xp[i * 256];
        float wrv = wrp[(size_t)i * 8192];
        float wiv = wip[(size_t)i * 8192];
        tr += xv.x * wrv - xv.y * wiv;
        ti += xv.x * wiv + xv.y * wrv;
    }
    pp[ig][t][0] = tr;
    pp[ig][t][1] = ti;
    __syncthreads();
    if (tid < 256) {
        tl[tid * 2 + 0] = pp[0][tid][0] + pp[1][tid][0] + pp[2][tid][0] + pp[3][tid][0];
        tl[tid * 2 + 1] = pp[0][tid][1] + pp[1][tid][1] + pp[2][tid][1] + pp[3][tid][1];
    }
    __syncthreads();

    int x = t, kg = ig;
    float gre[4], gim[4];
#pragma unroll
    for (int k = 0; k < 4; ++k) { gre[k] = 0.f; gim[k] = 0.f; }
#pragma unroll 4
    for (int kx = 0; kx < 16; ++kx) {
        int idx = (kx * x) & 255;
        float c = ct[idx], s = st[idx];
#pragma unroll
        for (int k = 0; k < 4; ++k) {
            int ky = kg * 4 + k;
            float t2r = tl[(kx * 16 + ky) * 2 + 0];
            float t2i = tl[(kx * 16 + ky) * 2 + 1];
            gre[k] += t2r * c - t2i * s;   // e^{+i}
            gim[k] += t2i * c + t2r * s;
        }
    }
    size_t ob = (((size_t)b * 256 + x) * 32 + o) * 32;
#pragma unroll
    for (int k = 0; k < 4; ++k) {
        gi[ob + (kg * 4 + k) * 2 + 0] = gre[k];
        gi[ob + (kg * 4 + k) * 2 + 1] = gim[k];
    }
}

// ---------------------------------------------------------------------------
// MFMA k_update + fused forward y-DFT of the NEW h (for the next layer).
// do_fy=0 on the last layer skips the DFT tail (uniform branch).
// ---------------------------------------------------------------------------
__global__ void __launch_bounds__(256) k_update(float* __restrict__ h,
        const float* __restrict__ gi,
        const short* __restrict__ wpwh, const short* __restrict__ wpwl,
        const float* __restrict__ pwb,
        const short* __restrict__ wifh, const short* __restrict__ wifl,
        const short* __restrict__ wfyh, const short* __restrict__ wfyl,
        float* __restrict__ gy, int do_fy) {
    __shared__ short hlsh[4][2048];
    __shared__ short hlsl[4][2048];
    __shared__ float red[4224];
    int tid = threadIdx.x;
    int wv = tid >> 6, l = tid & 63;
    int l15 = l & 15, lk = l >> 4;
    int bx = blockIdx.x, b = bx >> 8, x = bx & 255;
    float* hx = h + (((size_t)b * 32) << 16) + x * 256;   // + c*65536 + y

    // ---- A-frags: gt (runtime, from gi) and W (prepacked planes) ----
    bf16x8 gth[2], gtl[2], wh[2], wl[2];
    const float* gp = gi + (size_t)bx * 1024;
#pragma unroll
    for (int mt = 0; mt < 2; ++mt) {
        const float* ap = gp + (mt * 16 + l15) * 32 + lk * 8;
        float4 a0 = *(const float4*)ap;
        float4 a1 = *(const float4*)(ap + 4);
        float av[8] = {a0.x, a0.y, a0.z, a0.w, a1.x, a1.y, a1.z, a1.w};
#pragma unroll
        for (int j = 0; j < 8; ++j) {
            unsigned pb = pack_hl(av[j]);
            gth[mt][j] = (short)(pb >> 16);
            gtl[mt][j] = (short)(pb & 0xffffu);
        }
        int wbase = (mt * 16 + l15) * 32 + lk * 8;
        wh[mt] = *(const bf16x8*)(wpwh + wbase);
        wl[mt] = *(const bf16x8*)(wpwl + wbase);
    }

    // ---- MFMA phase ----
    f32x4 acc[2][4];
#pragma unroll
    for (int nt = 0; nt < 4; ++nt) {
        int y = wv * 64 + nt * 16 + l15;
        int ntg = wv * 4 + nt;
        int qb = ntg * 512 + l * 8;
        bf16x8 wih = *(const bf16x8*)(wifh + qb);
        bf16x8 wil = *(const bf16x8*)(wifl + qb);
        bf16x8 hbh, hbl;
#pragma unroll
        for (int j = 0; j < 8; ++j) {
            float v = hx[((size_t)(lk * 8 + j) << 16) + y];
            unsigned pb = pack_hl(v);
            hbh[j] = (short)(pb >> 16);
            hbl[j] = (short)(pb & 0xffffu);
        }
#pragma unroll
        for (int mt = 0; mt < 2; ++mt) {
            f32x4 a = {0.f, 0.f, 0.f, 0.f};
            a = __builtin_amdgcn_mfma_f32_16x16x32_bf16(gtl[mt], wih, a, 0, 0, 0);
            a = __builtin_amdgcn_mfma_f32_16x16x32_bf16(gth[mt], wil, a, 0, 0, 0);
            a = __builtin_amdgcn_mfma_f32_16x16x32_bf16(gth[mt], wih, a, 0, 0, 0);
            a = __builtin_amdgcn_mfma_f32_16x16x32_bf16(wl[mt],  hbh, a, 0, 0, 0);
            a = __builtin_amdgcn_mfma_f32_16x16x32_bf16(wh[mt],  hbl, a, 0, 0, 0);
            a = __builtin_amdgcn_mfma_f32_16x16x32_bf16(wh[mt],  hbh, a, 0, 0, 0);
            acc[mt][nt] = a;
        }
    }

    // ---- epilogue: h_old, gelu + residual, store global (+ LDS for DFT) ----
    float hold[2][4][4];
#pragma unroll
    for (int mt = 0; mt < 2; ++mt)
#pragma unroll
        for (int nt = 0; nt < 4; ++nt) {
            int y = wv * 64 + nt * 16 + l15;
#pragma unroll
            for (int r = 0; r < 4; ++r)
                hold[mt][nt][r] = hx[((size_t)(mt * 16 + lk * 4 + r) << 16) + y];
        }
#pragma unroll
    for (int mt = 0; mt < 2; ++mt)
#pragma unroll
        for (int nt = 0; nt < 4; ++nt) {
            int y = wv * 64 + nt * 16 + l15;
#pragma unroll
            for (int r = 0; r < 4; ++r) {
                int o = mt * 16 + lk * 4 + r;
                float u = acc[mt][nt][r] + pwb[o];
                float hn = hold[mt][nt][r] + gelu_f(u);
                hx[((size_t)o << 16) + y] = hn;
                if (do_fy) {
                    unsigned pb = pack_hl(hn);
                    int sl = (nt * 16 + l15) ^ ((o & 7) << 3);
                    hlsh[wv][o * 64 + sl] = (short)(pb >> 16);
                    hlsl[wv][o * 64 + sl] = (short)(pb & 0xffffu);
                }
            }
        }
    if (do_fy)
        dft_y_mfma(&hlsh[wv][0], &hlsl[wv][0], red, wfyh, wfyl, gy,
                   b, x, wv, lk, l15, tid);
}

// ---------------------------------------------------------------------------
// MFMA decoder (unchanged, passing at 163 us)
// ---------------------------------------------------------------------------
__global__ void __launch_bounds__(256) k_decode(const float* __restrict__ h,
        const short* __restrict__ wb1h, const short* __restrict__ wb1l,
        const float* __restrict__ b1,
        const short* __restrict__ wb2h, const short* __restrict__ wb2l,
        const float* __restrict__ b2,
        const float* __restrict__ w3, const float* __restrict__ b3,
        float* __restrict__ out) {
    __shared__ unsigned z1s[4][64][32];     // per-wave, XOR-swizzled 16B slots
    int tid = threadIdx.x;
    int wv = tid >> 6, l = tid & 63;
    int l15 = l & 15, lk = l >> 4;
    int b = blockIdx.x >> 8;
    int pos0 = (blockIdx.x & 255) * 256;

    bf16x8 ah[4], al[4];
    const float* hb = h + (((size_t)b * 32) << 16) + pos0;
#pragma unroll
    for (int mt = 0; mt < 4; ++mt) {
        int p = wv * 64 + mt * 16 + l15;
#pragma unroll
        for (int j = 0; j < 8; ++j) {
            float v = hb[((size_t)(lk * 8 + j) << 16) + p];
            unsigned pb = pack_hl(v);
            ah[mt][j] = (short)(pb >> 16);
            al[mt][j] = (short)(pb & 0xffffu);
        }
    }

    size_t gbase = (size_t)blockIdx.x * 256 + wv * 64;
    for (int d = 0; d < 3; ++d) {
        bf16x8 w1h[2], w1l[2];
        float bias1[2];
#pragma unroll
        for (int nb = 0; nb < 2; ++nb) {
            int base = ((d * 2 + nb) * 16 + l15) * 32 + lk * 8;
            w1h[nb] = *(const bf16x8*)(wb1h + base);
            w1l[nb] = *(const bf16x8*)(wb1l + base);
            bias1[nb] = b1[d * 32 + nb * 16 + l15];
        }
#pragma unroll
        for (int mt = 0; mt < 4; ++mt) {
#pragma unroll
            for (int nb = 0; nb < 2; ++nb) {
                f32x4 acc = {0.f, 0.f, 0.f, 0.f};
                acc = __builtin_amdgcn_mfma_f32_16x16x32_bf16(al[mt], w1h[nb], acc, 0, 0, 0);
                acc = __builtin_amdgcn_mfma_f32_16x16x32_bf16(ah[mt], w1l[nb], acc, 0, 0, 0);
                acc = __builtin_amdgcn_mfma_f32_16x16x32_bf16(ah[mt], w1h[nb], acc, 0, 0, 0);
                int c = nb * 16 + l15;
#pragma unroll
                for (int r = 0; r < 4; ++r) {
                    float z = gelu_f(acc[r] + bias1[nb]);
                    int rw = mt * 16 + lk * 4 + r;
                    z1s[wv][rw][(((c >> 2) ^ (rw & 7)) << 2) | (c & 3)] = pack_hl(z);
                }
            }
        }
        bf16x8 zah[4], zal[4];
#pragma unroll
        for (int mt = 0; mt < 4; ++mt) {
            int rwr = mt * 16 + l15;
            int sl0 = (2 * lk) ^ (rwr & 7);
            int sl1 = (2 * lk + 1) ^ (rwr & 7);
            u32x4 q0 = *(const u32x4*)&z1s[wv][rwr][sl0 << 2];
            u32x4 q1 = *(const u32x4*)&z1s[wv][rwr][sl1 << 2];
#pragma unroll
            for (int j = 0; j < 4; ++j) {
                zah[mt][j]     = (short)(q0[j] >> 16);
                zal[mt][j]     = (short)(q0[j] & 0xffffu);
                zah[mt][4 + j] = (short)(q1[j] >> 16);
                zal[mt][4 + j] = (short)(q1[j] & 0xffffu);
            }
        }
        float p3[4][4];
#pragma unroll
        for (int mt = 0; mt < 4; ++mt)
#pragma unroll
            for (int r = 0; r < 4; ++r) p3[mt][r] = 0.f;
#pragma unroll 2
        for (int blk = 0; blk < 8; ++blk) {
            int base = ((d * 8 + blk) * 16 + l15) * 32 + lk * 8;
            bf16x8 bh  = *(const bf16x8*)(wb2h + base);
            bf16x8 bl2 = *(const bf16x8*)(wb2l + base);
            float bias2 = b2[d * 128 + blk * 16 + l15];
            float w3v   = w3[d * 128 + blk * 16 + l15];
#pragma unroll
            for (int mt = 0; mt < 4; ++mt) {
                f32x4 acc = {0.f, 0.f, 0.f, 0.f};
                acc = __builtin_amdgcn_mfma_f32_16x16x32_bf16(zal[mt], bh, acc, 0, 0, 0);
                acc = __builtin_amdgcn_mfma_f32_16x16x32_bf16(zah[mt], bl2, acc, 0, 0, 0);
                acc = __builtin_amdgcn_mfma_f32_16x16x32_bf16(zah[mt], bh, acc, 0, 0, 0);
#pragma unroll
                for (int r = 0; r < 4; ++r)
                    p3[mt][r] = fmaf(gelu_f(acc[r] + bias2), w3v, p3[mt][r]);
            }
        }
        float b3d = b3[d];
#pragma unroll
        for (int mt = 0; mt < 4; ++mt) {
#pragma unroll
            for (int r = 0; r < 4; ++r) {
                float v = p3[mt][r];
                v += __shfl_xor(v, 1, 64);
                v += __shfl_xor(v, 2, 64);
                v += __shfl_xor(v, 4, 64);
                v += __shfl_xor(v, 8, 64);
                if (l15 == r)
                    out[(gbase + mt * 16 + lk * 4 + r) * 3 + d] = v + b3d;
            }
        }
    }
}

// ---------------------------------------------------------------------------
// Workspace (floats). gy and gi are now SEPARATE (update writes gy while
// reading gi). Total = 21,138,432 floats = 84,553,728 B — under round-1's
// proven-safe 84,934,656 B.
// ---------------------------------------------------------------------------
extern "C" void kernel_launch(void* const* d_in, const int* in_sizes, int n_in,
                              void* d_out, int out_size, void* d_ws, size_t ws_size,
                              hipStream_t stream) {
    const float* bc      = (const float*)d_in[0];
    const float* xg      = (const float*)d_in[1];
    const float* yg      = (const float*)d_in[2];
    const float* mlp1_w  = (const float*)d_in[3];
    const float* mlp1_b  = (const float*)d_in[4];
    const float* spec_wr = (const float*)d_in[5];
    const float* spec_wi = (const float*)d_in[6];
    const float* pw_w    = (const float*)d_in[7];
    const float* pw_b    = (const float*)d_in[8];
    const float* dec_w1  = (const float*)d_in[9];
    const float* dec_b1  = (const float*)d_in[10];
    const float* dec_w2  = (const float*)d_in[11];
    const float* dec_b2  = (const float*)d_in[12];
    const float* dec_w3  = (const float*)d_in[13];
    const float* dec_b3  = (const float*)d_in[14];
    float* out = (float*)d_out;

    float* h    = (float*)d_ws;               // 16,777,216 floats
    float* gi   = h + 16777216;               //  2,097,152
    float* gy   = gi + 2097152;               //  2,097,152
    float* Xf   = gy + 2097152;               //    131,072
    short* wb1h = (short*)(Xf + 131072);      //      3,072 shorts
    short* wb1l = wb1h + 3072;                //      3,072
    short* wb2h = wb1l + 3072;                //     12,288
    short* wb2l = wb2h + 12288;               //     12,288
    short* wpwh = wb2l + 12288;               //      4,096
    short* wpwl = wpwh + 4096;                //      4,096
    short* wifh = wpwl + 4096;                //      8,192
    short* wifl = wifh + 8192;                //      8,192
    short* wfyh = wifl + 8192;                //      8,192
    short* wfyl = wfyh + 8192;                //      8,192
    (void)ws_size; (void)n_in; (void)in_sizes; (void)out_size;

    k_prep<<<32, 256, 0, stream>>>(dec_w1, dec_w2, pw_w,
                                   wb1h, wb1l, wb2h, wb2l,
                                   wpwh, wpwl, wifh, wifl, wfyh, wfyl);
    k_lift_fy<<<2048, 256, 0, stream>>>(bc, xg, yg, mlp1_w, mlp1_b, h,
                                        wfyh, wfyl, gy);
    for (int l = 0; l < NL; ++l) {
        k_fwd_x<<<256, 1024, 0, stream>>>(gy, Xf);
        k_spec<<<256, 1024, 0, stream>>>(Xf, spec_wr + (size_t)l * 262144,
                                         spec_wi + (size_t)l * 262144, gi);
        k_update<<<2048, 256, 0, stream>>>(h, gi, wpwh + l * 1024, wpwl + l * 1024,
                                           pw_b + l * 32, wifh, wifl,
                                           wfyh, wfyl, gy, (l < NL - 1) ? 1 : 0);
    }
    k_decode<<<2048, 256, 0, stream>>>(h, wb1h, wb1l, dec_b1, wb2h, wb2l, dec_b2,
                                       dec_w3, dec_b3, out);
}